// Round 1
// baseline (2049.872 us; speedup 1.0000x reference)
//
#include <hip/hip_runtime.h>
#include <hip/hip_bf16.h>

#define T_TOK 8193
#define MROWS 16386        // B*T
#define NBLK  64
#define BS_   128

typedef __attribute__((ext_vector_type(8))) short bf16x8;
typedef __attribute__((ext_vector_type(4))) float f32x4;
typedef unsigned short u16;
typedef unsigned int   u32;

__device__ __forceinline__ float blo(u32 u){ return __uint_as_float(u << 16); }
__device__ __forceinline__ float bhi(u32 u){ return __uint_as_float(u & 0xffff0000u); }
__device__ __forceinline__ u16 f2b(float f){
  u32 u = __float_as_uint(f);
  u = (u + 0x7fffu + ((u >> 16) & 1u)) >> 16;
  return (u16)u;
}
__device__ __forceinline__ float b2f(u16 v){ return __uint_as_float(((u32)v) << 16); }

// ---------------- GEMM: C[M x N] = A[M x K] * B[K x N] (+bias) ----------------
// B given as up to 3 row-major parts each [K x bpart]; tile col-block selects part.
#define BMT 128
#define BNT 128
#define BKT 32
#define KP  40   // LDS row stride (elems): 80B rows -> 16B-aligned b128 frag reads

template<bool A_F32, bool OUT_F32>
__global__ __launch_bounds__(256)
void gemm_k(const void* __restrict__ Ap,
            const float* __restrict__ B0, const float* __restrict__ B1,
            const float* __restrict__ B2, int bpart,
            void* __restrict__ Cp, const float* __restrict__ bias,
            int M, int K, int lda, int ldc)
{
  __shared__ u16 As[BMT * KP];
  __shared__ u16 Bs[BNT * KP];
  const int tid  = threadIdx.x;
  const int lane = tid & 63;
  const int wid  = tid >> 6;
  const int wr   = (wid >> 1) * 64;
  const int wc   = (wid & 1) * 64;
  const int bm0  = blockIdx.x * BMT;
  const int bn0  = blockIdx.y * BNT;

  const int part  = bn0 / bpart;
  const float* Bm = (part == 0) ? B0 : ((part == 1) ? B1 : B2);
  const int bcol0 = bn0 - part * bpart;
  const int ldb   = bpart;

  f32x4 acc[4][4];
  #pragma unroll
  for (int i = 0; i < 4; ++i)
    #pragma unroll
    for (int j = 0; j < 4; ++j) { f32x4 z = {0.f,0.f,0.f,0.f}; acc[i][j] = z; }

  const int a_kq = (tid & 7) * 4;   // k quad within BK
  const int a_r0 = tid >> 3;        // 0..31
  const int b_cq = (tid & 31) * 4;  // col quad within BN
  const int b_k0 = tid >> 5;        // 0..7
  const int lrow = lane & 15;
  const int koff = (lane >> 4) * 8;

  for (int kt = 0; kt < K; kt += BKT) {
    __syncthreads();
    // ---- stage A tile (BMT x BKT), convert to bf16 ----
    #pragma unroll
    for (int rr = 0; rr < 4; ++rr) {
      int row  = a_r0 + rr * 32;
      int grow = bm0 + row;
      u16 s0, s1, s2, s3;
      if (A_F32) {
        float4 v = {0.f,0.f,0.f,0.f};
        if (grow < M) v = *(const float4*)((const float*)Ap + (size_t)grow * lda + kt + a_kq);
        s0 = f2b(v.x); s1 = f2b(v.y); s2 = f2b(v.z); s3 = f2b(v.w);
      } else {
        ushort4 v = {0,0,0,0};
        if (grow < M) v = *(const ushort4*)((const u16*)Ap + (size_t)grow * lda + kt + a_kq);
        s0 = v.x; s1 = v.y; s2 = v.z; s3 = v.w;
      }
      ushort4 st = {s0, s1, s2, s3};
      *(ushort4*)&As[row * KP + a_kq] = st;
    }
    // ---- stage B tile transposed: Bs[col][k] ----
    #pragma unroll
    for (int kk = 0; kk < 4; ++kk) {
      int k = b_k0 + kk * 8;
      float4 v = *(const float4*)(Bm + (size_t)(kt + k) * ldb + bcol0 + b_cq);
      Bs[(b_cq + 0) * KP + k] = f2b(v.x);
      Bs[(b_cq + 1) * KP + k] = f2b(v.y);
      Bs[(b_cq + 2) * KP + k] = f2b(v.z);
      Bs[(b_cq + 3) * KP + k] = f2b(v.w);
    }
    __syncthreads();
    // ---- fragments + MFMA ----
    bf16x8 af[4], bfr[4];
    #pragma unroll
    for (int mi = 0; mi < 4; ++mi)
      af[mi] = *(const bf16x8*)&As[(wr + mi * 16 + lrow) * KP + koff];
    #pragma unroll
    for (int ni = 0; ni < 4; ++ni)
      bfr[ni] = *(const bf16x8*)&Bs[(wc + ni * 16 + lrow) * KP + koff];
    #pragma unroll
    for (int mi = 0; mi < 4; ++mi)
      #pragma unroll
      for (int ni = 0; ni < 4; ++ni)
        acc[mi][ni] = __builtin_amdgcn_mfma_f32_16x16x32_bf16(af[mi], bfr[ni], acc[mi][ni], 0, 0, 0);
  }
  // ---- epilogue ----
  const int r0  = (lane >> 4) * 4;
  const int c0l = lane & 15;
  #pragma unroll
  for (int mi = 0; mi < 4; ++mi) {
    #pragma unroll
    for (int r = 0; r < 4; ++r) {
      int grow = bm0 + wr + mi * 16 + r0 + r;
      if (grow >= M) continue;
      #pragma unroll
      for (int ni = 0; ni < 4; ++ni) {
        int gcol  = bn0 + wc + ni * 16 + c0l;
        float val = acc[mi][ni][r];
        if (OUT_F32) ((float*)Cp)[(size_t)grow * ldc + gcol] = val + bias[gcol];
        else         ((u16*)Cp)[(size_t)grow * ldc + gcol]   = f2b(val);
      }
    }
  }
}

// ---------------- global-token attention: row t=0 per (b,h) ----------------
__global__ __launch_bounds__(256)
void global_attn(const u16* __restrict__ qkv, float* __restrict__ attn)
{
  const int b   = blockIdx.x >> 3;
  const int h   = blockIdx.x & 7;
  const int tid = threadIdx.x;
  const int lane = tid & 63;
  const int wid  = tid >> 6;
  __shared__ float sc[T_TOK];
  __shared__ float q0s[64];
  __shared__ float wredm[4], wreds[4];
  __shared__ float psum[4][64];

  const size_t base = (size_t)b * T_TOK * 1536;
  if (tid < 32) {
    u32 u = ((const u32*)(qkv + base + h * 64))[tid];
    q0s[2 * tid] = blo(u); q0s[2 * tid + 1] = bhi(u);
  }
  __syncthreads();

  float lmax = -INFINITY;
  for (int t = tid; t < T_TOK; t += 256) {
    const uint4* kp = (const uint4*)(qkv + base + (size_t)t * 1536 + 512 + h * 64);
    float a = 0.f;
    #pragma unroll
    for (int q8 = 0; q8 < 8; ++q8) {
      uint4 kk = kp[q8];
      a += q0s[q8*8+0]*blo(kk.x) + q0s[q8*8+1]*bhi(kk.x)
         + q0s[q8*8+2]*blo(kk.y) + q0s[q8*8+3]*bhi(kk.y)
         + q0s[q8*8+4]*blo(kk.z) + q0s[q8*8+5]*bhi(kk.z)
         + q0s[q8*8+6]*blo(kk.w) + q0s[q8*8+7]*bhi(kk.w);
    }
    a *= 0.125f;
    sc[t] = a;
    lmax = fmaxf(lmax, a);
  }
  for (int o = 32; o; o >>= 1) lmax = fmaxf(lmax, __shfl_xor(lmax, o, 64));
  if (lane == 0) wredm[wid] = lmax;
  __syncthreads();
  float bmax = fmaxf(fmaxf(wredm[0], wredm[1]), fmaxf(wredm[2], wredm[3]));
  float lsum = 0.f;
  for (int t = tid; t < T_TOK; t += 256) {
    float e = __expf(sc[t] - bmax);
    sc[t] = e;
    lsum += e;
  }
  for (int o = 32; o; o >>= 1) lsum += __shfl_xor(lsum, o, 64);
  if (lane == 0) wreds[wid] = lsum;
  __syncthreads();
  float bsum = wreds[0] + wreds[1] + wreds[2] + wreds[3];

  const int g = tid >> 6;
  const int d = tid & 63;
  float acc = 0.f;
  for (int t = g; t < T_TOK; t += 4)
    acc += sc[t] * b2f(qkv[base + (size_t)t * 1536 + 1024 + h * 64 + d]);
  psum[g][d] = acc;
  __syncthreads();
  if (tid < 64) {
    float o = (psum[0][tid] + psum[1][tid] + psum[2][tid] + psum[3][tid]) / bsum;
    attn[(size_t)b * T_TOK * 512 + h * 64 + tid] = o;
  }
}

// ---------------- block-local attention: one thread per query row ----------------
__device__ __forceinline__ float dot_row(const u16* __restrict__ qkv,
                                         const float* qf, size_t krow, int h)
{
  const uint4* kp = (const uint4*)(qkv + krow * 1536 + 512 + h * 64);
  float a = 0.f;
  #pragma unroll
  for (int t = 0; t < 8; ++t) {
    uint4 u = kp[t];
    a += qf[t*8+0]*blo(u.x) + qf[t*8+1]*bhi(u.x)
       + qf[t*8+2]*blo(u.y) + qf[t*8+3]*bhi(u.y)
       + qf[t*8+4]*blo(u.z) + qf[t*8+5]*bhi(u.z)
       + qf[t*8+6]*blo(u.w) + qf[t*8+7]*bhi(u.w);
  }
  return a * 0.125f;
}

__device__ __forceinline__ void add_v(const u16* __restrict__ qkv,
                                      float* o, size_t krow, int h, float p)
{
  const uint4* vp = (const uint4*)(qkv + krow * 1536 + 1024 + h * 64);
  #pragma unroll
  for (int t = 0; t < 8; ++t) {
    uint4 u = vp[t];
    o[t*8+0] += p * blo(u.x); o[t*8+1] += p * bhi(u.x);
    o[t*8+2] += p * blo(u.y); o[t*8+3] += p * bhi(u.y);
    o[t*8+4] += p * blo(u.z); o[t*8+5] += p * bhi(u.z);
    o[t*8+6] += p * blo(u.w); o[t*8+7] += p * bhi(u.w);
  }
}

__global__ __launch_bounds__(256)
void local_attn(const u16* __restrict__ qkv, float* __restrict__ attn)
{
  const int gidx = blockIdx.x * 256 + threadIdx.x;
  const int i = gidx & 127;
  const int n = (gidx >> 7) & 63;
  const int h = (gidx >> 13) & 7;
  const int b = gidx >> 16;
  const size_t qrow = (size_t)b * T_TOK + 1 + n * BS_ + i;

  float qf[64];
  {
    const uint4* qp = (const uint4*)(qkv + qrow * 1536 + h * 64);
    #pragma unroll
    for (int t = 0; t < 8; ++t) {
      uint4 u = qp[t];
      qf[t*8+0] = blo(u.x); qf[t*8+1] = bhi(u.x);
      qf[t*8+2] = blo(u.y); qf[t*8+3] = bhi(u.y);
      qf[t*8+4] = blo(u.z); qf[t*8+5] = bhi(u.z);
      qf[t*8+6] = blo(u.w); qf[t*8+7] = bhi(u.w);
    }
  }
  float o[64];
  #pragma unroll
  for (int d = 0; d < 64; ++d) o[d] = 0.f;
  float m = -INFINITY, l = 0.f;

  // global key (order within softmax is irrelevant)
  {
    size_t kr = (size_t)b * T_TOK;
    float s = dot_row(qkv, qf, kr, h);
    m = s;               // first key: max = s
    l = 1.f;             // exp(s - s)
    add_v(qkv, o, kr, h, 1.f);
  }
  // three neighbor blocks (valid ones); chunked by 8 keys to amortize rescale
  for (int nn = n - 1; nn <= n + 1; ++nn) {
    if (nn < 0 || nn >= NBLK) continue;
    size_t kb = (size_t)b * T_TOK + 1 + (size_t)nn * BS_;
    for (int c0 = 0; c0 < BS_; c0 += 8) {
      float s[8];
      #pragma unroll
      for (int c = 0; c < 8; ++c) s[c] = dot_row(qkv, qf, kb + c0 + c, h);
      float cm = s[0];
      #pragma unroll
      for (int c = 1; c < 8; ++c) cm = fmaxf(cm, s[c]);
      float mn   = fmaxf(m, cm);
      float corr = __expf(m - mn);
      l *= corr;
      #pragma unroll
      for (int d = 0; d < 64; ++d) o[d] *= corr;
      #pragma unroll
      for (int c = 0; c < 8; ++c) {
        float p = __expf(s[c] - mn);
        l += p;
        add_v(qkv, o, kb + c0 + c, h, p);
      }
      m = mn;
    }
  }
  // zero-padded boundary blocks: 128 keys with score exactly 0, V = 0
  int nz = (n == 0) + (n == NBLK - 1);
  if (nz) {
    float mn   = fmaxf(m, 0.f);
    float corr = __expf(m - mn);
    l = l * corr + (float)(nz * BS_) * __expf(0.f - mn);
    #pragma unroll
    for (int d = 0; d < 64; ++d) o[d] *= corr;
  }
  float inv = 1.f / l;
  float4* op = (float4*)(attn + qrow * 512 + h * 64);
  #pragma unroll
  for (int t = 0; t < 16; ++t) {
    float4 st = { o[t*4+0]*inv, o[t*4+1]*inv, o[t*4+2]*inv, o[t*4+3]*inv };
    op[t] = st;
  }
}

extern "C" void kernel_launch(void* const* d_in, const int* in_sizes, int n_in,
                              void* d_out, int out_size, void* d_ws, size_t ws_size,
                              hipStream_t stream) {
  (void)in_sizes; (void)n_in; (void)out_size; (void)ws_size;
  const float* x  = (const float*)d_in[0];
  const float* Wq = (const float*)d_in[1];
  const float* Wk = (const float*)d_in[2];
  const float* Wv = (const float*)d_in[3];
  const float* Wo = (const float*)d_in[4];
  const float* bo = (const float*)d_in[5];
  float* out = (float*)d_out;

  u16*   qkv  = (u16*)d_ws;                                        // [16386][1536] bf16
  float* attn = (float*)((char*)d_ws + (size_t)MROWS * 1536 * 2);  // [16386][512] f32

  dim3 blk(256);
  // QKV projection: N=1536 over {Wq,Wk,Wv} (each K=1024 x 512)
  gemm_k<true, false><<<dim3(129, 12), blk, 0, stream>>>(
      x, Wq, Wk, Wv, 512, qkv, nullptr, MROWS, 1024, 1024, 1536);
  // attention
  global_attn<<<dim3(16), blk, 0, stream>>>(qkv, attn);
  local_attn<<<dim3(512), blk, 0, stream>>>(qkv, attn);
  // output projection: N=1024, K=512, fp32 A, fp32 out + bias
  gemm_k<true, true><<<dim3(129, 8), blk, 0, stream>>>(
      attn, Wo, Wo, Wo, 1024, out, bo, MROWS, 512, 512, 1024);
}

// Round 2
// 507.926 us; speedup vs baseline: 4.0358x; 4.0358x over previous
//
#include <hip/hip_runtime.h>
#include <hip/hip_bf16.h>

#define T_TOK 8193
#define MROWS 16386        // B*T
#define NBLK  64
#define BS_   128
#define GCH   16           // global-attn chunks per (b,h)
#define GCS   513          // chunk size (16*513 >= 8193)

typedef __attribute__((ext_vector_type(8))) short bf16x8;
typedef __attribute__((ext_vector_type(4))) float f32x4;
typedef unsigned short u16;
typedef unsigned int   u32;

__device__ __forceinline__ float blo(u32 u){ return __uint_as_float(u << 16); }
__device__ __forceinline__ float bhi(u32 u){ return __uint_as_float(u & 0xffff0000u); }
__device__ __forceinline__ u16 f2b(float f){
  u32 u = __float_as_uint(f);
  u = (u + 0x7fffu + ((u >> 16) & 1u)) >> 16;
  return (u16)u;
}
__device__ __forceinline__ float b2f(u16 v){ return __uint_as_float(((u32)v) << 16); }

// ---------------- GEMM: C[M x N] = A[M x K] * B[K x N] (+bias) ----------------
#define BMT 128
#define BNT 128
#define BKT 32
#define KP  40

template<bool A_F32, bool OUT_F32>
__global__ __launch_bounds__(256)
void gemm_k(const void* __restrict__ Ap,
            const float* __restrict__ B0, const float* __restrict__ B1,
            const float* __restrict__ B2, int bpart,
            void* __restrict__ Cp, const float* __restrict__ bias,
            int M, int K, int lda, int ldc)
{
  __shared__ u16 As[BMT * KP];
  __shared__ u16 Bs[BNT * KP];
  const int tid  = threadIdx.x;
  const int lane = tid & 63;
  const int wid  = tid >> 6;
  const int wr   = (wid >> 1) * 64;
  const int wc   = (wid & 1) * 64;
  const int bm0  = blockIdx.x * BMT;
  const int bn0  = blockIdx.y * BNT;

  const int part  = bn0 / bpart;
  const float* Bm = (part == 0) ? B0 : ((part == 1) ? B1 : B2);
  const int bcol0 = bn0 - part * bpart;
  const int ldb   = bpart;

  f32x4 acc[4][4];
  #pragma unroll
  for (int i = 0; i < 4; ++i)
    #pragma unroll
    for (int j = 0; j < 4; ++j) { f32x4 z = {0.f,0.f,0.f,0.f}; acc[i][j] = z; }

  const int a_kq = (tid & 7) * 4;
  const int a_r0 = tid >> 3;
  const int b_cq = (tid & 31) * 4;
  const int b_k0 = tid >> 5;
  const int lrow = lane & 15;
  const int koff = (lane >> 4) * 8;

  for (int kt = 0; kt < K; kt += BKT) {
    __syncthreads();
    #pragma unroll
    for (int rr = 0; rr < 4; ++rr) {
      int row  = a_r0 + rr * 32;
      int grow = bm0 + row;
      u16 s0, s1, s2, s3;
      if (A_F32) {
        float4 v = {0.f,0.f,0.f,0.f};
        if (grow < M) v = *(const float4*)((const float*)Ap + (size_t)grow * lda + kt + a_kq);
        s0 = f2b(v.x); s1 = f2b(v.y); s2 = f2b(v.z); s3 = f2b(v.w);
      } else {
        ushort4 v = {0,0,0,0};
        if (grow < M) v = *(const ushort4*)((const u16*)Ap + (size_t)grow * lda + kt + a_kq);
        s0 = v.x; s1 = v.y; s2 = v.z; s3 = v.w;
      }
      ushort4 st = {s0, s1, s2, s3};
      *(ushort4*)&As[row * KP + a_kq] = st;
    }
    #pragma unroll
    for (int kk = 0; kk < 4; ++kk) {
      int k = b_k0 + kk * 8;
      float4 v = *(const float4*)(Bm + (size_t)(kt + k) * ldb + bcol0 + b_cq);
      Bs[(b_cq + 0) * KP + k] = f2b(v.x);
      Bs[(b_cq + 1) * KP + k] = f2b(v.y);
      Bs[(b_cq + 2) * KP + k] = f2b(v.z);
      Bs[(b_cq + 3) * KP + k] = f2b(v.w);
    }
    __syncthreads();
    bf16x8 af[4], bfr[4];
    #pragma unroll
    for (int mi = 0; mi < 4; ++mi)
      af[mi] = *(const bf16x8*)&As[(wr + mi * 16 + lrow) * KP + koff];
    #pragma unroll
    for (int ni = 0; ni < 4; ++ni)
      bfr[ni] = *(const bf16x8*)&Bs[(wc + ni * 16 + lrow) * KP + koff];
    #pragma unroll
    for (int mi = 0; mi < 4; ++mi)
      #pragma unroll
      for (int ni = 0; ni < 4; ++ni)
        acc[mi][ni] = __builtin_amdgcn_mfma_f32_16x16x32_bf16(af[mi], bfr[ni], acc[mi][ni], 0, 0, 0);
  }
  const int r0  = (lane >> 4) * 4;
  const int c0l = lane & 15;
  #pragma unroll
  for (int mi = 0; mi < 4; ++mi) {
    #pragma unroll
    for (int r = 0; r < 4; ++r) {
      int grow = bm0 + wr + mi * 16 + r0 + r;
      if (grow >= M) continue;
      #pragma unroll
      for (int ni = 0; ni < 4; ++ni) {
        int gcol  = bn0 + wc + ni * 16 + c0l;
        float val = acc[mi][ni][r];
        if (OUT_F32) ((float*)Cp)[(size_t)grow * ldc + gcol] = val + bias[gcol];
        else         ((u16*)Cp)[(size_t)grow * ldc + gcol]   = f2b(val);
      }
    }
  }
}

// ---------------- global-token attention, split into chunks ----------------
__global__ __launch_bounds__(256)
void gsplit(const u16* __restrict__ qkv, float* __restrict__ gbuf)
{
  const int c   = blockIdx.x & 15;
  const int h   = (blockIdx.x >> 4) & 7;
  const int b   = blockIdx.x >> 7;
  const int tid = threadIdx.x;
  const int lane = tid & 63;
  const int wid  = tid >> 6;
  const int t0 = c * GCS;
  const int t1 = (t0 + GCS < T_TOK) ? (t0 + GCS) : T_TOK;
  const int nt = t1 - t0;

  __shared__ float sc[GCS];
  __shared__ float q0s[64];
  __shared__ float wredm[4], wreds[4];
  __shared__ float psum[4][64];

  const size_t base = (size_t)b * T_TOK * 1536;
  if (tid < 32) {
    u32 u = ((const u32*)(qkv + base + h * 64))[tid];
    q0s[2 * tid] = blo(u); q0s[2 * tid + 1] = bhi(u);
  }
  __syncthreads();

  float lmax = -INFINITY;
  for (int tt = tid; tt < nt; tt += 256) {
    const uint4* kp = (const uint4*)(qkv + base + (size_t)(t0 + tt) * 1536 + 512 + h * 64);
    float a = 0.f;
    #pragma unroll
    for (int q8 = 0; q8 < 8; ++q8) {
      uint4 kk = kp[q8];
      a += q0s[q8*8+0]*blo(kk.x) + q0s[q8*8+1]*bhi(kk.x)
         + q0s[q8*8+2]*blo(kk.y) + q0s[q8*8+3]*bhi(kk.y)
         + q0s[q8*8+4]*blo(kk.z) + q0s[q8*8+5]*bhi(kk.z)
         + q0s[q8*8+6]*blo(kk.w) + q0s[q8*8+7]*bhi(kk.w);
    }
    a *= 0.125f;
    sc[tt] = a;
    lmax = fmaxf(lmax, a);
  }
  for (int o = 32; o; o >>= 1) lmax = fmaxf(lmax, __shfl_xor(lmax, o, 64));
  if (lane == 0) wredm[wid] = lmax;
  __syncthreads();
  float bmax = fmaxf(fmaxf(wredm[0], wredm[1]), fmaxf(wredm[2], wredm[3]));
  float lsum = 0.f;
  for (int tt = tid; tt < nt; tt += 256) {
    float e = __expf(sc[tt] - bmax);
    sc[tt] = e;
    lsum += e;
  }
  for (int o = 32; o; o >>= 1) lsum += __shfl_xor(lsum, o, 64);
  if (lane == 0) wreds[wid] = lsum;
  __syncthreads();
  float bsum = wreds[0] + wreds[1] + wreds[2] + wreds[3];

  const int g = tid >> 6;
  const int d = tid & 63;
  float acc = 0.f;
  for (int tt = g; tt < nt; tt += 4)
    acc += sc[tt] * b2f(qkv[base + (size_t)(t0 + tt) * 1536 + 1024 + h * 64 + d]);
  psum[g][d] = acc;
  __syncthreads();

  float* rec = gbuf + ((size_t)(b * 8 + h) * GCH + c) * 66;
  if (tid < 64)
    rec[2 + tid] = psum[0][tid] + psum[1][tid] + psum[2][tid] + psum[3][tid];
  if (tid == 64) { rec[0] = bmax; rec[1] = bsum; }
}

__global__ __launch_bounds__(64)
void gmerge(const float* __restrict__ gbuf, float* __restrict__ attn)
{
  const int bh = blockIdx.x;
  const int d  = threadIdx.x;
  const float* recs = gbuf + (size_t)bh * GCH * 66;
  float m = -INFINITY;
  #pragma unroll
  for (int c = 0; c < GCH; ++c) m = fmaxf(m, recs[c * 66]);
  float l = 0.f, o = 0.f;
  #pragma unroll
  for (int c = 0; c < GCH; ++c) {
    float e = __expf(recs[c * 66] - m);
    l += recs[c * 66 + 1] * e;
    o += recs[c * 66 + 2 + d] * e;
  }
  const int b = bh >> 3, h = bh & 7;
  attn[(size_t)b * T_TOK * 512 + h * 64 + d] = o / l;
}

// ---------------- block-local attention: MFMA flash, 1 workgroup per (b,h,n) ----------------
__global__ __launch_bounds__(256)
void local_attn_mfma(const u16* __restrict__ qkv, float* __restrict__ attn)
{
  const int bid = blockIdx.x;
  const int n = bid & 63;
  const int h = (bid >> 6) & 7;
  const int b = bid >> 9;
  const int tid  = threadIdx.x;
  const int lane = tid & 63;
  const int wid  = tid >> 6;
  const int l15  = lane & 15;
  const int g    = lane >> 4;

  __shared__ u16 K_lds[128 * 72];      // [key][72]
  __shared__ u16 V_T[64 * 136];        // [d][136] (transposed V)
  __shared__ u16 P_lds[4][32 * 72];    // per-wave, 64-key half-chunks
  __shared__ float bb[4][2][32];
  __shared__ float Kg[64], Vg[64];

  const size_t rb = (size_t)b * T_TOK;
  if (tid < 64) {
    Kg[tid] = b2f(qkv[rb * 1536 + 512 + h * 64 + tid]);
    Vg[tid] = b2f(qkv[rb * 1536 + 1024 + h * 64 + tid]);
  }

  // Q fragments (B-frag layout: lane holds q=l15(+16qt), k = kk*32 + g*8 .. +8)
  const int q0row = 1 + n * 128 + wid * 32;
  bf16x8 qf[2][2];
  #pragma unroll
  for (int qt = 0; qt < 2; ++qt)
    #pragma unroll
    for (int kk = 0; kk < 2; ++kk)
      qf[qt][kk] = *(const bf16x8*)(qkv + (rb + q0row + qt * 16 + l15) * 1536 + h * 64 + kk * 32 + g * 8);

  __syncthreads();

  // global-key scores
  float sg[2];
  #pragma unroll
  for (int qt = 0; qt < 2; ++qt) {
    float part = 0.f;
    #pragma unroll
    for (int kk = 0; kk < 2; ++kk)
      #pragma unroll
      for (int i = 0; i < 8; ++i)
        part += b2f((u16)qf[qt][kk][i]) * Kg[kk * 32 + g * 8 + i];
    part += __shfl_xor(part, 16, 64);
    part += __shfl_xor(part, 32, 64);
    sg[qt] = part * 0.125f;
  }

  float m[2] = {-INFINITY, -INFINITY};
  float l[2] = {0.f, 0.f};
  f32x4 of[2][4];
  #pragma unroll
  for (int qt = 0; qt < 2; ++qt)
    #pragma unroll
    for (int dt = 0; dt < 4; ++dt) { f32x4 z = {0.f,0.f,0.f,0.f}; of[qt][dt] = z; }

  for (int dblk = 0; dblk < 3; ++dblk) {
    const int blk = n + dblk - 1;
    if (blk < 0 || blk >= NBLK) continue;
    const size_t krow0 = rb + 1 + (size_t)blk * 128;

    __syncthreads();    // protect K_lds/V_T from previous iteration's readers
    // stage K [128][64] -> K_lds[key*72 + oct*8], coalesced 16B chunks
    #pragma unroll
    for (int it = 0; it < 4; ++it) {
      int c = it * 256 + tid;
      int key = c >> 3, oct = c & 7;
      *(uint4*)&K_lds[key * 72 + oct * 8] =
          *(const uint4*)(qkv + (krow0 + key) * 1536 + 512 + h * 64 + oct * 8);
    }
    // stage V transposed: thread handles key-pair (2kp,2kp+1) x 8 dims -> u32 column writes
    #pragma unroll
    for (int it = 0; it < 2; ++it) {
      int c = it * 256 + tid;
      int kp2 = c & 63, oct = c >> 6;
      const u16* s0 = qkv + (krow0 + 2 * kp2) * 1536 + 1024 + h * 64 + oct * 8;
      uint4 va = *(const uint4*)s0;
      uint4 vb4 = *(const uint4*)(s0 + 1536);
      union { uint4 q; u16 hh[8]; } ua, ub;
      ua.q = va; ub.q = vb4;
      #pragma unroll
      for (int i = 0; i < 8; ++i) {
        u32 w = (u32)ua.hh[i] | ((u32)ub.hh[i] << 16);
        *(u32*)&V_T[(oct * 8 + i) * 136 + 2 * kp2] = w;
      }
    }
    __syncthreads();

    // S^T = K * Q^T  (C layout: lane&15 = q, rows = key)
    f32x4 st[2][8];
    #pragma unroll
    for (int kt = 0; kt < 8; ++kt) {
      bf16x8 kfr[2];
      #pragma unroll
      for (int kk = 0; kk < 2; ++kk)
        kfr[kk] = *(const bf16x8*)&K_lds[(kt * 16 + l15) * 72 + kk * 32 + g * 8];
      #pragma unroll
      for (int qt = 0; qt < 2; ++qt) {
        f32x4 z = {0.f,0.f,0.f,0.f};
        z = __builtin_amdgcn_mfma_f32_16x16x32_bf16(kfr[0], qf[qt][0], z, 0, 0, 0);
        z = __builtin_amdgcn_mfma_f32_16x16x32_bf16(kfr[1], qf[qt][1], z, 0, 0, 0);
        st[qt][kt] = z;
      }
    }
    // online softmax (scores scaled by 0.125 at use)
    #pragma unroll
    for (int qt = 0; qt < 2; ++qt) {
      float bm = -INFINITY;
      #pragma unroll
      for (int kt = 0; kt < 8; ++kt)
        #pragma unroll
        for (int r = 0; r < 4; ++r) bm = fmaxf(bm, st[qt][kt][r]);
      bm = fmaxf(bm, __shfl_xor(bm, 16, 64));
      bm = fmaxf(bm, __shfl_xor(bm, 32, 64));
      bm *= 0.125f;
      float mn = fmaxf(m[qt], bm);
      float corr = __expf(m[qt] - mn);
      float bsum = 0.f;
      #pragma unroll
      for (int kt = 0; kt < 8; ++kt)
        #pragma unroll
        for (int r = 0; r < 4; ++r) {
          float p = __expf(__builtin_fmaf(st[qt][kt][r], 0.125f, -mn));
          st[qt][kt][r] = p;
          bsum += p;
        }
      bsum += __shfl_xor(bsum, 16, 64);
      bsum += __shfl_xor(bsum, 32, 64);
      l[qt] = l[qt] * corr + bsum;
      m[qt] = mn;
      if (lane < 16) bb[wid][0][qt * 16 + lane] = corr;
    }
    // rescale O by corr (broadcast via wave-local LDS)
    float rc[2][4];
    #pragma unroll
    for (int qt = 0; qt < 2; ++qt)
      #pragma unroll
      for (int r = 0; r < 4; ++r) rc[qt][r] = bb[wid][0][qt * 16 + g * 4 + r];
    #pragma unroll
    for (int qt = 0; qt < 2; ++qt)
      #pragma unroll
      for (int dt = 0; dt < 4; ++dt)
        #pragma unroll
        for (int r = 0; r < 4; ++r) of[qt][dt][r] *= rc[qt][r];

    // PV in two 64-key halves through per-wave P buffer
    u16* P_w = (u16*)P_lds[wid];
    #pragma unroll
    for (int half = 0; half < 2; ++half) {
      #pragma unroll
      for (int qt = 0; qt < 2; ++qt)
        #pragma unroll
        for (int k4 = 0; k4 < 4; ++k4) {
          int kt = half * 4 + k4;
          u16 h0 = f2b(st[qt][kt][0]), h1 = f2b(st[qt][kt][1]);
          u16 h2 = f2b(st[qt][kt][2]), h3 = f2b(st[qt][kt][3]);
          uint2 pk = { (u32)h0 | ((u32)h1 << 16), (u32)h2 | ((u32)h3 << 16) };
          *(uint2*)&P_w[(qt * 16 + l15) * 72 + k4 * 16 + g * 4] = pk;
        }
      #pragma unroll
      for (int ks = 0; ks < 2; ++ks) {
        bf16x8 pa[2];
        #pragma unroll
        for (int qt = 0; qt < 2; ++qt)
          pa[qt] = *(const bf16x8*)&P_w[(qt * 16 + l15) * 72 + ks * 32 + g * 8];
        #pragma unroll
        for (int dt = 0; dt < 4; ++dt) {
          bf16x8 vb = *(const bf16x8*)&V_T[(dt * 16 + l15) * 136 + half * 64 + ks * 32 + g * 8];
          #pragma unroll
          for (int qt = 0; qt < 2; ++qt)
            of[qt][dt] = __builtin_amdgcn_mfma_f32_16x16x32_bf16(pa[qt], vb, of[qt][dt], 0, 0, 0);
        }
      }
    }
  }

  // final fold: global key + boundary zero-pad blocks
  const int nz = (n == 0) + (n == NBLK - 1);
  #pragma unroll
  for (int qt = 0; qt < 2; ++qt) {
    float mf   = fmaxf(m[qt], sg[qt]);
    float corr = __expf(m[qt] - mf);
    float eg   = __expf(sg[qt] - mf);
    float lf   = l[qt] * corr + eg;
    if (nz) lf += (float)(nz * 128) * __expf(-mf);
    float inv = 1.f / lf;
    if (lane < 16) {
      bb[wid][0][qt * 16 + lane] = corr * inv;
      bb[wid][1][qt * 16 + lane] = eg * inv;
    }
  }
  float vgr[4];
  #pragma unroll
  for (int dt = 0; dt < 4; ++dt) vgr[dt] = Vg[dt * 16 + l15];
  #pragma unroll
  for (int qt = 0; qt < 2; ++qt)
    #pragma unroll
    for (int r = 0; r < 4; ++r) {
      float af = bb[wid][0][qt * 16 + g * 4 + r];
      float bf = bb[wid][1][qt * 16 + g * 4 + r];
      int row = q0row + qt * 16 + g * 4 + r;
      float* dst = attn + (rb + row) * 512 + h * 64;
      #pragma unroll
      for (int dt = 0; dt < 4; ++dt)
        dst[dt * 16 + l15] = of[qt][dt][r] * af + bf * vgr[dt];
    }
}

extern "C" void kernel_launch(void* const* d_in, const int* in_sizes, int n_in,
                              void* d_out, int out_size, void* d_ws, size_t ws_size,
                              hipStream_t stream) {
  (void)in_sizes; (void)n_in; (void)out_size; (void)ws_size;
  const float* x  = (const float*)d_in[0];
  const float* Wq = (const float*)d_in[1];
  const float* Wk = (const float*)d_in[2];
  const float* Wv = (const float*)d_in[3];
  const float* Wo = (const float*)d_in[4];
  const float* bo = (const float*)d_in[5];
  float* out = (float*)d_out;

  u16*   qkv  = (u16*)d_ws;                                        // [16386][1536] bf16
  float* attn = (float*)((char*)d_ws + (size_t)MROWS * 1536 * 2);  // [16386][512] f32
  float* gbuf = out;  // scratch for global-attn partials; gemm2 overwrites d_out after

  dim3 blk(256);
  gemm_k<true, false><<<dim3(129, 12), blk, 0, stream>>>(
      x, Wq, Wk, Wv, 512, qkv, nullptr, MROWS, 1024, 1024, 1536);
  gsplit<<<dim3(256), blk, 0, stream>>>(qkv, gbuf);
  gmerge<<<dim3(16), dim3(64), 0, stream>>>(gbuf, attn);
  local_attn_mfma<<<dim3(1024), blk, 0, stream>>>(qkv, attn);
  gemm_k<true, true><<<dim3(129, 8), blk, 0, stream>>>(
      attn, Wo, Wo, Wo, 1024, out, bo, MROWS, 512, 512, 1024);
}

// Round 3
// 233.251 us; speedup vs baseline: 8.7883x; 2.1776x over previous
//
#include <hip/hip_runtime.h>
#include <hip/hip_bf16.h>

#define T_TOK 8193
#define MROWS 16386        // B*T
#define NBLK  64
#define GCH   16           // global-attn chunks per (b,h)
#define GCS   513          // chunk size (16*513 >= 8193)

typedef __attribute__((ext_vector_type(8))) short bf16x8;
typedef __attribute__((ext_vector_type(4))) float f32x4;
typedef unsigned short u16;
typedef unsigned int   u32;

__device__ __forceinline__ float blo(u32 u){ return __uint_as_float(u << 16); }
__device__ __forceinline__ float bhi(u32 u){ return __uint_as_float(u & 0xffff0000u); }
__device__ __forceinline__ u16 f2b(float f){
  u32 u = __float_as_uint(f);
  u = (u + 0x7fffu + ((u >> 16) & 1u)) >> 16;
  return (u16)u;
}
__device__ __forceinline__ float b2f(u16 v){ return __uint_as_float(((u32)v) << 16); }

#define GLDS16(gsrc, ldst) \
  __builtin_amdgcn_global_load_lds((const __attribute__((address_space(1))) void*)(gsrc), \
                                   (__attribute__((address_space(3))) void*)(ldst), 16, 0, 0)

// ---------------- x -> bf16 ----------------
__global__ __launch_bounds__(256)
void convx(const float* __restrict__ x, u16* __restrict__ xb)
{
  const size_t i = (size_t)blockIdx.x * 256 + threadIdx.x;
  const float4* p = (const float4*)x + i * 2;
  float4 a = p[0], b = p[1];
  uint4 st;
  st.x = (u32)f2b(a.x) | ((u32)f2b(a.y) << 16);
  st.y = (u32)f2b(a.z) | ((u32)f2b(a.w) << 16);
  st.z = (u32)f2b(b.x) | ((u32)f2b(b.y) << 16);
  st.w = (u32)f2b(b.z) | ((u32)f2b(b.w) << 16);
  *(uint4*)(xb + i * 8) = st;
}

// ---------------- W [K][N] fp32 (up to 3 parts) -> W^T [N][K] bf16 ----------------
__global__ __launch_bounds__(256)
void transposeW(const float* __restrict__ B0, const float* __restrict__ B1,
                const float* __restrict__ B2, int bpart,
                u16* __restrict__ outT, int K)
{
  __shared__ float tile[64][65];
  const int n0 = blockIdx.x * 64;
  const int k0 = blockIdx.y * 64;
  const int tx = threadIdx.x & 63;
  const int ty = threadIdx.x >> 6;
  const int part = n0 / bpart;
  const float* Bm = part == 0 ? B0 : (part == 1 ? B1 : B2);
  const int bn = n0 - part * bpart;
  #pragma unroll
  for (int i = 0; i < 16; ++i) {
    int k = i * 4 + ty;
    tile[tx][k] = Bm[(size_t)(k0 + k) * bpart + bn + tx];
  }
  __syncthreads();
  #pragma unroll
  for (int i = 0; i < 16; ++i) {
    int r = i * 4 + ty;
    outT[(size_t)(n0 + r) * K + k0 + tx] = f2b(tile[r][tx]);
  }
}

// ---------------- GEMM: C[M x N] = A[M x K] * BT[N x K]^T, m97 structure ----------------
template<bool OUT_F32>
__global__ __launch_bounds__(256)
void gemm_bf(const u16* __restrict__ A, const u16* __restrict__ BT,
             void* __restrict__ Cp, const float* __restrict__ bias,
             int M, int K, int ntm, int ldc)
{
  __shared__ u16 As[128 * 32];
  __shared__ u16 Bs[128 * 32];
  const int tid  = threadIdx.x;
  const int lane = tid & 63;
  const int wid  = tid >> 6;
  const int l15  = lane & 15;
  const int g    = lane >> 4;
  const int wr   = (wid >> 1) * 64;
  const int wc   = (wid & 1) * 64;

  // bijective XCD swizzle (m204), tm-major within an N-strip
  const int nwg  = gridDim.x;
  const int orig = blockIdx.x;
  const int q8 = nwg >> 3, r8 = nwg & 7;
  const int xcd = orig & 7, loc = orig >> 3;
  const int wg = (xcd < r8 ? xcd * (q8 + 1) : r8 * (q8 + 1) + (xcd - r8) * q8) + loc;
  const int tm = wg % ntm, tn = wg / ntm;
  const int bm0 = tm * 128, bn0 = tn * 128;

  f32x4 acc[4][4];
  #pragma unroll
  for (int i = 0; i < 4; ++i)
    #pragma unroll
    for (int j = 0; j < 4; ++j) { f32x4 z = {0.f,0.f,0.f,0.f}; acc[i][j] = z; }

  // staging: 512 x 16B chunks per tile, 2 per thread; linear LDS dest
  const int c0 = tid, c1 = tid + 256;
  int ar0 = bm0 + (c0 >> 2); if (ar0 >= M) ar0 = M - 1;
  int ar1 = bm0 + (c1 >> 2); if (ar1 >= M) ar1 = M - 1;
  const u16* Ag0 = A + (size_t)ar0 * K + (c0 & 3) * 8;
  const u16* Ag1 = A + (size_t)ar1 * K + (c1 & 3) * 8;
  const u16* Bg0 = BT + (size_t)(bn0 + (c0 >> 2)) * K + (c0 & 3) * 8;
  const u16* Bg1 = BT + (size_t)(bn0 + (c1 >> 2)) * K + (c1 & 3) * 8;
  u16* la0 = As + c0 * 8;  u16* la1 = As + c1 * 8;
  u16* lb0 = Bs + c0 * 8;  u16* lb1 = Bs + c1 * 8;

  for (int kt = 0; kt < K; kt += 32) {
    __syncthreads();
    GLDS16(Ag0 + kt, la0);
    GLDS16(Ag1 + kt, la1);
    GLDS16(Bg0 + kt, lb0);
    GLDS16(Bg1 + kt, lb1);
    __syncthreads();
    bf16x8 af[4], bfr[4];
    #pragma unroll
    for (int mi = 0; mi < 4; ++mi)
      af[mi] = *(const bf16x8*)&As[(wr + mi * 16 + l15) * 32 + g * 8];
    #pragma unroll
    for (int ni = 0; ni < 4; ++ni)
      bfr[ni] = *(const bf16x8*)&Bs[(wc + ni * 16 + l15) * 32 + g * 8];
    #pragma unroll
    for (int mi = 0; mi < 4; ++mi)
      #pragma unroll
      for (int ni = 0; ni < 4; ++ni)
        acc[mi][ni] = __builtin_amdgcn_mfma_f32_16x16x32_bf16(af[mi], bfr[ni], acc[mi][ni], 0, 0, 0);
  }

  const int r0 = g * 4;
  #pragma unroll
  for (int mi = 0; mi < 4; ++mi) {
    #pragma unroll
    for (int r = 0; r < 4; ++r) {
      int grow = bm0 + wr + mi * 16 + r0 + r;
      if (grow >= M) continue;
      #pragma unroll
      for (int ni = 0; ni < 4; ++ni) {
        int gcol  = bn0 + wc + ni * 16 + l15;
        float val = acc[mi][ni][r];
        if (OUT_F32) ((float*)Cp)[(size_t)grow * ldc + gcol] = val + bias[gcol];
        else         ((u16*)Cp)[(size_t)grow * ldc + gcol]   = f2b(val);
      }
    }
  }
}

// ---------------- global-token attention, split into chunks ----------------
__global__ __launch_bounds__(256)
void gsplit(const u16* __restrict__ qkv, float* __restrict__ gbuf)
{
  const int c   = blockIdx.x & 15;
  const int h   = (blockIdx.x >> 4) & 7;
  const int b   = blockIdx.x >> 7;
  const int tid = threadIdx.x;
  const int lane = tid & 63;
  const int wid  = tid >> 6;
  const int t0 = c * GCS;
  const int t1 = (t0 + GCS < T_TOK) ? (t0 + GCS) : T_TOK;
  const int nt = t1 - t0;

  __shared__ float sc[GCS];
  __shared__ float q0s[64];
  __shared__ float wredm[4], wreds[4];
  __shared__ float psum[4][64];

  const size_t base = (size_t)b * T_TOK * 1536;
  if (tid < 32) {
    u32 u = ((const u32*)(qkv + base + h * 64))[tid];
    q0s[2 * tid] = blo(u); q0s[2 * tid + 1] = bhi(u);
  }
  __syncthreads();

  float lmax = -INFINITY;
  for (int tt = tid; tt < nt; tt += 256) {
    const uint4* kp = (const uint4*)(qkv + base + (size_t)(t0 + tt) * 1536 + 512 + h * 64);
    float a = 0.f;
    #pragma unroll
    for (int q8 = 0; q8 < 8; ++q8) {
      uint4 kk = kp[q8];
      a += q0s[q8*8+0]*blo(kk.x) + q0s[q8*8+1]*bhi(kk.x)
         + q0s[q8*8+2]*blo(kk.y) + q0s[q8*8+3]*bhi(kk.y)
         + q0s[q8*8+4]*blo(kk.z) + q0s[q8*8+5]*bhi(kk.z)
         + q0s[q8*8+6]*blo(kk.w) + q0s[q8*8+7]*bhi(kk.w);
    }
    a *= 0.125f;
    sc[tt] = a;
    lmax = fmaxf(lmax, a);
  }
  for (int o = 32; o; o >>= 1) lmax = fmaxf(lmax, __shfl_xor(lmax, o, 64));
  if (lane == 0) wredm[wid] = lmax;
  __syncthreads();
  float bmax = fmaxf(fmaxf(wredm[0], wredm[1]), fmaxf(wredm[2], wredm[3]));
  float lsum = 0.f;
  for (int tt = tid; tt < nt; tt += 256) {
    float e = __expf(sc[tt] - bmax);
    sc[tt] = e;
    lsum += e;
  }
  for (int o = 32; o; o >>= 1) lsum += __shfl_xor(lsum, o, 64);
  if (lane == 0) wreds[wid] = lsum;
  __syncthreads();
  float bsum = wreds[0] + wreds[1] + wreds[2] + wreds[3];

  const int g = tid >> 6;
  const int d = tid & 63;
  float acc = 0.f;
  for (int tt = g; tt < nt; tt += 4)
    acc += sc[tt] * b2f(qkv[base + (size_t)(t0 + tt) * 1536 + 1024 + h * 64 + d]);
  psum[g][d] = acc;
  __syncthreads();

  float* rec = gbuf + ((size_t)(b * 8 + h) * GCH + c) * 66;
  if (tid < 64)
    rec[2 + tid] = psum[0][tid] + psum[1][tid] + psum[2][tid] + psum[3][tid];
  if (tid == 64) { rec[0] = bmax; rec[1] = bsum; }
}

__global__ __launch_bounds__(64)
void gmerge(const float* __restrict__ gbuf, u16* __restrict__ attnb)
{
  const int bh = blockIdx.x;
  const int d  = threadIdx.x;
  const float* recs = gbuf + (size_t)bh * GCH * 66;
  float m = -INFINITY;
  #pragma unroll
  for (int c = 0; c < GCH; ++c) m = fmaxf(m, recs[c * 66]);
  float l = 0.f, o = 0.f;
  #pragma unroll
  for (int c = 0; c < GCH; ++c) {
    float e = __expf(recs[c * 66] - m);
    l += recs[c * 66 + 1] * e;
    o += recs[c * 66 + 2 + d] * e;
  }
  const int b = bh >> 3, h = bh & 7;
  attnb[(size_t)b * T_TOK * 512 + h * 64 + d] = f2b(o / l);
}

// ---------------- block-local attention: MFMA flash, 1 workgroup per (b,h,n) ----------------
__global__ __launch_bounds__(256)
void local_attn_mfma(const u16* __restrict__ qkv, u16* __restrict__ attnb)
{
  const int bid = blockIdx.x;
  const int n = bid & 63;
  const int h = (bid >> 6) & 7;
  const int b = bid >> 9;
  const int tid  = threadIdx.x;
  const int lane = tid & 63;
  const int wid  = tid >> 6;
  const int l15  = lane & 15;
  const int g    = lane >> 4;

  __shared__ u16 K_lds[128 * 72];
  __shared__ u16 V_T[64 * 136];
  __shared__ u16 P_lds[4][32 * 72];
  __shared__ float bb[4][2][32];
  __shared__ float Kg[64], Vg[64];

  const size_t rb = (size_t)b * T_TOK;
  if (tid < 64) {
    Kg[tid] = b2f(qkv[rb * 1536 + 512 + h * 64 + tid]);
    Vg[tid] = b2f(qkv[rb * 1536 + 1024 + h * 64 + tid]);
  }

  const int q0row = 1 + n * 128 + wid * 32;
  bf16x8 qf[2][2];
  #pragma unroll
  for (int qt = 0; qt < 2; ++qt)
    #pragma unroll
    for (int kk = 0; kk < 2; ++kk)
      qf[qt][kk] = *(const bf16x8*)(qkv + (rb + q0row + qt * 16 + l15) * 1536 + h * 64 + kk * 32 + g * 8);

  __syncthreads();

  float sg[2];
  #pragma unroll
  for (int qt = 0; qt < 2; ++qt) {
    float part = 0.f;
    #pragma unroll
    for (int kk = 0; kk < 2; ++kk)
      #pragma unroll
      for (int i = 0; i < 8; ++i)
        part += b2f((u16)qf[qt][kk][i]) * Kg[kk * 32 + g * 8 + i];
    part += __shfl_xor(part, 16, 64);
    part += __shfl_xor(part, 32, 64);
    sg[qt] = part * 0.125f;
  }

  float m[2] = {-INFINITY, -INFINITY};
  float l[2] = {0.f, 0.f};
  f32x4 of[2][4];
  #pragma unroll
  for (int qt = 0; qt < 2; ++qt)
    #pragma unroll
    for (int dt = 0; dt < 4; ++dt) { f32x4 z = {0.f,0.f,0.f,0.f}; of[qt][dt] = z; }

  for (int dblk = 0; dblk < 3; ++dblk) {
    const int blk = n + dblk - 1;
    if (blk < 0 || blk >= NBLK) continue;
    const size_t krow0 = rb + 1 + (size_t)blk * 128;

    __syncthreads();
    #pragma unroll
    for (int it = 0; it < 4; ++it) {
      int c = it * 256 + tid;
      int key = c >> 3, oct = c & 7;
      *(uint4*)&K_lds[key * 72 + oct * 8] =
          *(const uint4*)(qkv + (krow0 + key) * 1536 + 512 + h * 64 + oct * 8);
    }
    #pragma unroll
    for (int it = 0; it < 2; ++it) {
      int c = it * 256 + tid;
      int kp2 = c & 63, oct = c >> 6;
      const u16* s0 = qkv + (krow0 + 2 * kp2) * 1536 + 1024 + h * 64 + oct * 8;
      uint4 va = *(const uint4*)s0;
      uint4 vb4 = *(const uint4*)(s0 + 1536);
      union { uint4 q; u16 hh[8]; } ua, ub;
      ua.q = va; ub.q = vb4;
      #pragma unroll
      for (int i = 0; i < 8; ++i) {
        u32 w = (u32)ua.hh[i] | ((u32)ub.hh[i] << 16);
        *(u32*)&V_T[(oct * 8 + i) * 136 + 2 * kp2] = w;
      }
    }
    __syncthreads();

    f32x4 st[2][8];
    #pragma unroll
    for (int kt = 0; kt < 8; ++kt) {
      bf16x8 kfr[2];
      #pragma unroll
      for (int kk = 0; kk < 2; ++kk)
        kfr[kk] = *(const bf16x8*)&K_lds[(kt * 16 + l15) * 72 + kk * 32 + g * 8];
      #pragma unroll
      for (int qt = 0; qt < 2; ++qt) {
        f32x4 z = {0.f,0.f,0.f,0.f};
        z = __builtin_amdgcn_mfma_f32_16x16x32_bf16(kfr[0], qf[qt][0], z, 0, 0, 0);
        z = __builtin_amdgcn_mfma_f32_16x16x32_bf16(kfr[1], qf[qt][1], z, 0, 0, 0);
        st[qt][kt] = z;
      }
    }
    #pragma unroll
    for (int qt = 0; qt < 2; ++qt) {
      float bm = -INFINITY;
      #pragma unroll
      for (int kt = 0; kt < 8; ++kt)
        #pragma unroll
        for (int r = 0; r < 4; ++r) bm = fmaxf(bm, st[qt][kt][r]);
      bm = fmaxf(bm, __shfl_xor(bm, 16, 64));
      bm = fmaxf(bm, __shfl_xor(bm, 32, 64));
      bm *= 0.125f;
      float mn = fmaxf(m[qt], bm);
      float corr = __expf(m[qt] - mn);
      float bsum = 0.f;
      #pragma unroll
      for (int kt = 0; kt < 8; ++kt)
        #pragma unroll
        for (int r = 0; r < 4; ++r) {
          float p = __expf(__builtin_fmaf(st[qt][kt][r], 0.125f, -mn));
          st[qt][kt][r] = p;
          bsum += p;
        }
      bsum += __shfl_xor(bsum, 16, 64);
      bsum += __shfl_xor(bsum, 32, 64);
      l[qt] = l[qt] * corr + bsum;
      m[qt] = mn;
      if (lane < 16) bb[wid][0][qt * 16 + lane] = corr;
    }
    float rc[2][4];
    #pragma unroll
    for (int qt = 0; qt < 2; ++qt)
      #pragma unroll
      for (int r = 0; r < 4; ++r) rc[qt][r] = bb[wid][0][qt * 16 + g * 4 + r];
    #pragma unroll
    for (int qt = 0; qt < 2; ++qt)
      #pragma unroll
      for (int dt = 0; dt < 4; ++dt)
        #pragma unroll
        for (int r = 0; r < 4; ++r) of[qt][dt][r] *= rc[qt][r];

    u16* P_w = (u16*)P_lds[wid];
    #pragma unroll
    for (int half = 0; half < 2; ++half) {
      #pragma unroll
      for (int qt = 0; qt < 2; ++qt)
        #pragma unroll
        for (int k4 = 0; k4 < 4; ++k4) {
          int kt = half * 4 + k4;
          u16 h0 = f2b(st[qt][kt][0]), h1 = f2b(st[qt][kt][1]);
          u16 h2 = f2b(st[qt][kt][2]), h3 = f2b(st[qt][kt][3]);
          uint2 pk = { (u32)h0 | ((u32)h1 << 16), (u32)h2 | ((u32)h3 << 16) };
          *(uint2*)&P_w[(qt * 16 + l15) * 72 + k4 * 16 + g * 4] = pk;
        }
      #pragma unroll
      for (int ks = 0; ks < 2; ++ks) {
        bf16x8 pa[2];
        #pragma unroll
        for (int qt = 0; qt < 2; ++qt)
          pa[qt] = *(const bf16x8*)&P_w[(qt * 16 + l15) * 72 + ks * 32 + g * 8];
        #pragma unroll
        for (int dt = 0; dt < 4; ++dt) {
          bf16x8 vb = *(const bf16x8*)&V_T[(dt * 16 + l15) * 136 + half * 64 + ks * 32 + g * 8];
          #pragma unroll
          for (int qt = 0; qt < 2; ++qt)
            of[qt][dt] = __builtin_amdgcn_mfma_f32_16x16x32_bf16(pa[qt], vb, of[qt][dt], 0, 0, 0);
        }
      }
    }
  }

  const int nz = (n == 0) + (n == NBLK - 1);
  #pragma unroll
  for (int qt = 0; qt < 2; ++qt) {
    float mf   = fmaxf(m[qt], sg[qt]);
    float corr = __expf(m[qt] - mf);
    float eg   = __expf(sg[qt] - mf);
    float lf   = l[qt] * corr + eg;
    if (nz) lf += (float)(nz * 128) * __expf(-mf);
    float inv = 1.f / lf;
    if (lane < 16) {
      bb[wid][0][qt * 16 + lane] = corr * inv;
      bb[wid][1][qt * 16 + lane] = eg * inv;
    }
  }
  float vgr[4];
  #pragma unroll
  for (int dt = 0; dt < 4; ++dt) vgr[dt] = Vg[dt * 16 + l15];
  #pragma unroll
  for (int qt = 0; qt < 2; ++qt)
    #pragma unroll
    for (int r = 0; r < 4; ++r) {
      float af = bb[wid][0][qt * 16 + g * 4 + r];
      float bf = bb[wid][1][qt * 16 + g * 4 + r];
      int row = q0row + qt * 16 + g * 4 + r;
      u16* dst = attnb + (rb + row) * 512 + h * 64;
      #pragma unroll
      for (int dt = 0; dt < 4; ++dt)
        dst[dt * 16 + l15] = f2b(of[qt][dt][r] * af + bf * vgr[dt]);
    }
}

extern "C" void kernel_launch(void* const* d_in, const int* in_sizes, int n_in,
                              void* d_out, int out_size, void* d_ws, size_t ws_size,
                              hipStream_t stream) {
  (void)in_sizes; (void)n_in; (void)out_size; (void)ws_size;
  const float* x  = (const float*)d_in[0];
  const float* Wq = (const float*)d_in[1];
  const float* Wk = (const float*)d_in[2];
  const float* Wv = (const float*)d_in[3];
  const float* Wo = (const float*)d_in[4];
  const float* bo = (const float*)d_in[5];
  float* out = (float*)d_out;

  char* ws = (char*)d_ws;
  // ws layout (peak exactly 83,896,320 B as in the passing r1/r2 runs):
  //   [0, 50337792)                 qkv bf16 [16386][1536]
  //   [50337792, 83896320)          xb bf16 [16386][1024]   (dead after gemm1)
  //   [50337792, 67117056)          attnb bf16 [16386][512] (reuses xb)
  //   [67117056, 68165632)          WoT bf16 [1024][512]    (reuses xb)
  u16* qkv   = (u16*)ws;
  u16* xb    = (u16*)(ws + 50337792);
  u16* attnb = (u16*)(ws + 50337792);
  u16* WoT   = (u16*)(ws + 67117056);
  u16* WqkvT = (u16*)d_out;                              // scratch; dead before gemm2
  float* gbuf = (float*)((char*)d_out + (4 << 20));      // 33 KB partials

  dim3 blk(256);
  convx<<<dim3(8193), blk, 0, stream>>>(x, xb);
  transposeW<<<dim3(24, 16), blk, 0, stream>>>(Wq, Wk, Wv, 512, WqkvT, 1024);
  gemm_bf<false><<<dim3(129 * 12), blk, 0, stream>>>(xb, WqkvT, qkv, nullptr, MROWS, 1024, 129, 1536);
  transposeW<<<dim3(16, 8), blk, 0, stream>>>(Wo, Wo, Wo, 1024, WoT, 512);
  gsplit<<<dim3(256), blk, 0, stream>>>(qkv, gbuf);
  gmerge<<<dim3(16), dim3(64), 0, stream>>>(gbuf, attnb);
  local_attn_mfma<<<dim3(1024), blk, 0, stream>>>(qkv, attnb);
  gemm_bf<true><<<dim3(129 * 8), blk, 0, stream>>>(attnb, WoT, out, bo, MROWS, 512, 129, 1024);
}

// Round 4
// 227.687 us; speedup vs baseline: 9.0030x; 1.0244x over previous
//
#include <hip/hip_runtime.h>
#include <hip/hip_bf16.h>

#define T_TOK 8193
#define MROWS 16386        // B*T
#define NBLK  64
#define GCH   16           // global-attn chunks per (b,h)
#define GCS   513          // chunk size (16*513 >= 8193)

typedef __attribute__((ext_vector_type(8))) short bf16x8;
typedef __attribute__((ext_vector_type(4))) float f32x4;
typedef unsigned short u16;
typedef unsigned int   u32;

__device__ __forceinline__ float blo(u32 u){ return __uint_as_float(u << 16); }
__device__ __forceinline__ float bhi(u32 u){ return __uint_as_float(u & 0xffff0000u); }
__device__ __forceinline__ u16 f2b(float f){
  u32 u = __float_as_uint(f);
  u = (u + 0x7fffu + ((u >> 16) & 1u)) >> 16;
  return (u16)u;
}
__device__ __forceinline__ float b2f(u16 v){ return __uint_as_float(((u32)v) << 16); }

#define GLDS16(gsrc, ldst) \
  __builtin_amdgcn_global_load_lds((const __attribute__((address_space(1))) void*)(gsrc), \
                                   (__attribute__((address_space(3))) void*)(ldst), 16, 0, 0)

// ---------------- x -> bf16 ----------------
__global__ __launch_bounds__(256)
void convx(const float* __restrict__ x, u16* __restrict__ xb)
{
  const size_t i = (size_t)blockIdx.x * 256 + threadIdx.x;
  const float4* p = (const float4*)x + i * 2;
  float4 a = p[0], b = p[1];
  uint4 st;
  st.x = (u32)f2b(a.x) | ((u32)f2b(a.y) << 16);
  st.y = (u32)f2b(a.z) | ((u32)f2b(a.w) << 16);
  st.z = (u32)f2b(b.x) | ((u32)f2b(b.y) << 16);
  st.w = (u32)f2b(b.z) | ((u32)f2b(b.w) << 16);
  *(uint4*)(xb + i * 8) = st;
}

// ---------------- W [K][N] fp32 (up to 3 parts) -> W^T [N][K] bf16 ----------------
__global__ __launch_bounds__(256)
void transposeW(const float* __restrict__ B0, const float* __restrict__ B1,
                const float* __restrict__ B2, int bpart,
                u16* __restrict__ outT, int K)
{
  __shared__ float tile[64][65];
  const int n0 = blockIdx.x * 64;
  const int k0 = blockIdx.y * 64;
  const int tx = threadIdx.x & 63;
  const int ty = threadIdx.x >> 6;
  const int part = n0 / bpart;
  const float* Bm = part == 0 ? B0 : (part == 1 ? B1 : B2);
  const int bn = n0 - part * bpart;
  #pragma unroll
  for (int i = 0; i < 16; ++i) {
    int k = i * 4 + ty;
    tile[tx][k] = Bm[(size_t)(k0 + k) * bpart + bn + tx];
  }
  __syncthreads();
  #pragma unroll
  for (int i = 0; i < 16; ++i) {
    int r = i * 4 + ty;
    outT[(size_t)(n0 + r) * K + k0 + tx] = f2b(tile[r][tx]);
  }
}

// ---------------- GEMM: C[M x N] = A[M x K] * BT[N x K]^T, m97 structure ----------------
// Block order: bijective XCD swizzle (m204) -> A-strip groups (GT tm-tiles),
// tn-major within a group, so each XCD keeps a 2MB A-strip + whole B L2-resident.
template<bool OUT_F32>
__global__ __launch_bounds__(256)
void gemm_bf(const u16* __restrict__ A, const u16* __restrict__ BT,
             void* __restrict__ Cp, const float* __restrict__ bias,
             int M, int K, int ntm, int ntn, int ldc)
{
  __shared__ u16 As[128 * 32];
  __shared__ u16 Bs[128 * 32];
  const int tid  = threadIdx.x;
  const int lane = tid & 63;
  const int wid  = tid >> 6;
  const int l15  = lane & 15;
  const int g    = lane >> 4;
  const int wr   = (wid >> 1) * 64;
  const int wc   = (wid & 1) * 64;

  const int nwg  = gridDim.x;
  const int orig = blockIdx.x;
  const int q8 = nwg >> 3, r8 = nwg & 7;
  const int xcd = orig & 7, loc = orig >> 3;
  const int wg = (xcd < r8 ? xcd * (q8 + 1) : r8 * (q8 + 1) + (xcd - r8) * q8) + loc;
  // A-strip grouped order
  const int GT  = 8;
  const int gsz = GT * ntn;
  const int tg  = wg / gsz;
  const int rem = wg - tg * gsz;
  const int gt  = (ntm - tg * GT < GT) ? (ntm - tg * GT) : GT;
  const int tn  = rem / gt;
  const int tml = rem - tn * gt;
  const int tm  = tg * GT + tml;
  const int bm0 = tm * 128, bn0 = tn * 128;

  f32x4 acc[4][4];
  #pragma unroll
  for (int i = 0; i < 4; ++i)
    #pragma unroll
    for (int j = 0; j < 4; ++j) { f32x4 z = {0.f,0.f,0.f,0.f}; acc[i][j] = z; }

  // staging: 512 x 16B chunks per tile, 2 per thread; linear LDS dest
  const int c0 = tid, c1 = tid + 256;
  int ar0 = bm0 + (c0 >> 2); if (ar0 >= M) ar0 = M - 1;
  int ar1 = bm0 + (c1 >> 2); if (ar1 >= M) ar1 = M - 1;
  const u16* Ag0 = A + (size_t)ar0 * K + (c0 & 3) * 8;
  const u16* Ag1 = A + (size_t)ar1 * K + (c1 & 3) * 8;
  const u16* Bg0 = BT + (size_t)(bn0 + (c0 >> 2)) * K + (c0 & 3) * 8;
  const u16* Bg1 = BT + (size_t)(bn0 + (c1 >> 2)) * K + (c1 & 3) * 8;
  u16* la0 = As + c0 * 8;  u16* la1 = As + c1 * 8;
  u16* lb0 = Bs + c0 * 8;  u16* lb1 = Bs + c1 * 8;

  for (int kt = 0; kt < K; kt += 32) {
    __syncthreads();
    GLDS16(Ag0 + kt, la0);
    GLDS16(Ag1 + kt, la1);
    GLDS16(Bg0 + kt, lb0);
    GLDS16(Bg1 + kt, lb1);
    __syncthreads();
    bf16x8 af[4], bfr[4];
    #pragma unroll
    for (int mi = 0; mi < 4; ++mi)
      af[mi] = *(const bf16x8*)&As[(wr + mi * 16 + l15) * 32 + g * 8];
    #pragma unroll
    for (int ni = 0; ni < 4; ++ni)
      bfr[ni] = *(const bf16x8*)&Bs[(wc + ni * 16 + l15) * 32 + g * 8];
    #pragma unroll
    for (int mi = 0; mi < 4; ++mi)
      #pragma unroll
      for (int ni = 0; ni < 4; ++ni)
        acc[mi][ni] = __builtin_amdgcn_mfma_f32_16x16x32_bf16(af[mi], bfr[ni], acc[mi][ni], 0, 0, 0);
  }

  const int r0 = g * 4;
  #pragma unroll
  for (int mi = 0; mi < 4; ++mi) {
    #pragma unroll
    for (int r = 0; r < 4; ++r) {
      int grow = bm0 + wr + mi * 16 + r0 + r;
      if (grow >= M) continue;
      #pragma unroll
      for (int ni = 0; ni < 4; ++ni) {
        int gcol  = bn0 + wc + ni * 16 + l15;
        float val = acc[mi][ni][r];
        if (OUT_F32) ((float*)Cp)[(size_t)grow * ldc + gcol] = val + bias[gcol];
        else         ((u16*)Cp)[(size_t)grow * ldc + gcol]   = f2b(val);
      }
    }
  }
}

// ---------------- global-token attention, split into chunks ----------------
__global__ __launch_bounds__(256)
void gsplit(const u16* __restrict__ qkv, float* __restrict__ gbuf)
{
  const int c   = blockIdx.x & 15;
  const int h   = (blockIdx.x >> 4) & 7;
  const int b   = blockIdx.x >> 7;
  const int tid = threadIdx.x;
  const int lane = tid & 63;
  const int wid  = tid >> 6;
  const int t0 = c * GCS;
  const int t1 = (t0 + GCS < T_TOK) ? (t0 + GCS) : T_TOK;
  const int nt = t1 - t0;

  __shared__ float sc[GCS];
  __shared__ float q0s[64];
  __shared__ float wredm[4], wreds[4];
  __shared__ float psum[4][64];

  const size_t base = (size_t)b * T_TOK * 1536;
  if (tid < 32) {
    u32 u = ((const u32*)(qkv + base + h * 64))[tid];
    q0s[2 * tid] = blo(u); q0s[2 * tid + 1] = bhi(u);
  }
  __syncthreads();

  float lmax = -INFINITY;
  for (int tt = tid; tt < nt; tt += 256) {
    const uint4* kp = (const uint4*)(qkv + base + (size_t)(t0 + tt) * 1536 + 512 + h * 64);
    float a = 0.f;
    #pragma unroll
    for (int q8 = 0; q8 < 8; ++q8) {
      uint4 kk = kp[q8];
      a += q0s[q8*8+0]*blo(kk.x) + q0s[q8*8+1]*bhi(kk.x)
         + q0s[q8*8+2]*blo(kk.y) + q0s[q8*8+3]*bhi(kk.y)
         + q0s[q8*8+4]*blo(kk.z) + q0s[q8*8+5]*bhi(kk.z)
         + q0s[q8*8+6]*blo(kk.w) + q0s[q8*8+7]*bhi(kk.w);
    }
    a *= 0.125f;
    sc[tt] = a;
    lmax = fmaxf(lmax, a);
  }
  for (int o = 32; o; o >>= 1) lmax = fmaxf(lmax, __shfl_xor(lmax, o, 64));
  if (lane == 0) wredm[wid] = lmax;
  __syncthreads();
  float bmax = fmaxf(fmaxf(wredm[0], wredm[1]), fmaxf(wredm[2], wredm[3]));
  float lsum = 0.f;
  for (int tt = tid; tt < nt; tt += 256) {
    float e = __expf(sc[tt] - bmax);
    sc[tt] = e;
    lsum += e;
  }
  for (int o = 32; o; o >>= 1) lsum += __shfl_xor(lsum, o, 64);
  if (lane == 0) wreds[wid] = lsum;
  __syncthreads();
  float bsum = wreds[0] + wreds[1] + wreds[2] + wreds[3];

  const int g = tid >> 6;
  const int d = tid & 63;
  float acc = 0.f;
  for (int tt = g; tt < nt; tt += 4)
    acc += sc[tt] * b2f(qkv[base + (size_t)(t0 + tt) * 1536 + 1024 + h * 64 + d]);
  psum[g][d] = acc;
  __syncthreads();

  float* rec = gbuf + ((size_t)(b * 8 + h) * GCH + c) * 66;
  if (tid < 64)
    rec[2 + tid] = psum[0][tid] + psum[1][tid] + psum[2][tid] + psum[3][tid];
  if (tid == 64) { rec[0] = bmax; rec[1] = bsum; }
}

__global__ __launch_bounds__(64)
void gmerge(const float* __restrict__ gbuf, u16* __restrict__ attnb)
{
  const int bh = blockIdx.x;
  const int d  = threadIdx.x;
  const float* recs = gbuf + (size_t)bh * GCH * 66;
  float m = -INFINITY;
  #pragma unroll
  for (int c = 0; c < GCH; ++c) m = fmaxf(m, recs[c * 66]);
  float l = 0.f, o = 0.f;
  #pragma unroll
  for (int c = 0; c < GCH; ++c) {
    float e = __expf(recs[c * 66] - m);
    l += recs[c * 66 + 1] * e;
    o += recs[c * 66 + 2 + d] * e;
  }
  const int b = bh >> 3, h = bh & 7;
  attnb[(size_t)b * T_TOK * 512 + h * 64 + d] = f2b(o / l);
}

// ---------------- block-local attention: MFMA flash, 1 workgroup per (b,h,n) ----------------
__global__ __launch_bounds__(256)
void local_attn_mfma(const u16* __restrict__ qkv, u16* __restrict__ attnb)
{
  const int bid = blockIdx.x;
  const int n = bid & 63;
  const int h = (bid >> 6) & 7;
  const int b = bid >> 9;
  const int tid  = threadIdx.x;
  const int lane = tid & 63;
  const int wid  = tid >> 6;
  const int l15  = lane & 15;
  const int g    = lane >> 4;

  __shared__ u16 K_lds[128 * 72];
  __shared__ u16 V_T[64 * 136];
  __shared__ u16 P_lds[4][32 * 72];
  __shared__ float bb[4][2][32];
  __shared__ float Kg[64], Vg[64];

  const size_t rb = (size_t)b * T_TOK;
  if (tid < 64) {
    Kg[tid] = b2f(qkv[rb * 1536 + 512 + h * 64 + tid]);
    Vg[tid] = b2f(qkv[rb * 1536 + 1024 + h * 64 + tid]);
  }

  const int q0row = 1 + n * 128 + wid * 32;
  bf16x8 qf[2][2];
  #pragma unroll
  for (int qt = 0; qt < 2; ++qt)
    #pragma unroll
    for (int kk = 0; kk < 2; ++kk)
      qf[qt][kk] = *(const bf16x8*)(qkv + (rb + q0row + qt * 16 + l15) * 1536 + h * 64 + kk * 32 + g * 8);

  __syncthreads();

  float sg[2];
  #pragma unroll
  for (int qt = 0; qt < 2; ++qt) {
    float part = 0.f;
    #pragma unroll
    for (int kk = 0; kk < 2; ++kk)
      #pragma unroll
      for (int i = 0; i < 8; ++i)
        part += b2f((u16)qf[qt][kk][i]) * Kg[kk * 32 + g * 8 + i];
    part += __shfl_xor(part, 16, 64);
    part += __shfl_xor(part, 32, 64);
    sg[qt] = part * 0.125f;
  }

  float m[2] = {-INFINITY, -INFINITY};
  float l[2] = {0.f, 0.f};
  f32x4 of[2][4];
  #pragma unroll
  for (int qt = 0; qt < 2; ++qt)
    #pragma unroll
    for (int dt = 0; dt < 4; ++dt) { f32x4 z = {0.f,0.f,0.f,0.f}; of[qt][dt] = z; }

  for (int dblk = 0; dblk < 3; ++dblk) {
    const int blk = n + dblk - 1;
    if (blk < 0 || blk >= NBLK) continue;
    const size_t krow0 = rb + 1 + (size_t)blk * 128;

    __syncthreads();
    #pragma unroll
    for (int it = 0; it < 4; ++it) {
      int c = it * 256 + tid;
      int key = c >> 3, oct = c & 7;
      *(uint4*)&K_lds[key * 72 + oct * 8] =
          *(const uint4*)(qkv + (krow0 + key) * 1536 + 512 + h * 64 + oct * 8);
    }
    #pragma unroll
    for (int it = 0; it < 2; ++it) {
      int c = it * 256 + tid;
      int kp2 = c & 63, oct = c >> 6;
      const u16* s0 = qkv + (krow0 + 2 * kp2) * 1536 + 1024 + h * 64 + oct * 8;
      uint4 va = *(const uint4*)s0;
      uint4 vb4 = *(const uint4*)(s0 + 1536);
      union { uint4 q; u16 hh[8]; } ua, ub;
      ua.q = va; ub.q = vb4;
      #pragma unroll
      for (int i = 0; i < 8; ++i) {
        u32 w = (u32)ua.hh[i] | ((u32)ub.hh[i] << 16);
        *(u32*)&V_T[(oct * 8 + i) * 136 + 2 * kp2] = w;
      }
    }
    __syncthreads();

    f32x4 st[2][8];
    #pragma unroll
    for (int kt = 0; kt < 8; ++kt) {
      bf16x8 kfr[2];
      #pragma unroll
      for (int kk = 0; kk < 2; ++kk)
        kfr[kk] = *(const bf16x8*)&K_lds[(kt * 16 + l15) * 72 + kk * 32 + g * 8];
      #pragma unroll
      for (int qt = 0; qt < 2; ++qt) {
        f32x4 z = {0.f,0.f,0.f,0.f};
        z = __builtin_amdgcn_mfma_f32_16x16x32_bf16(kfr[0], qf[qt][0], z, 0, 0, 0);
        z = __builtin_amdgcn_mfma_f32_16x16x32_bf16(kfr[1], qf[qt][1], z, 0, 0, 0);
        st[qt][kt] = z;
      }
    }
    #pragma unroll
    for (int qt = 0; qt < 2; ++qt) {
      float bm = -INFINITY;
      #pragma unroll
      for (int kt = 0; kt < 8; ++kt)
        #pragma unroll
        for (int r = 0; r < 4; ++r) bm = fmaxf(bm, st[qt][kt][r]);
      bm = fmaxf(bm, __shfl_xor(bm, 16, 64));
      bm = fmaxf(bm, __shfl_xor(bm, 32, 64));
      bm *= 0.125f;
      float mn = fmaxf(m[qt], bm);
      float corr = __expf(m[qt] - mn);
      float bsum = 0.f;
      #pragma unroll
      for (int kt = 0; kt < 8; ++kt)
        #pragma unroll
        for (int r = 0; r < 4; ++r) {
          float p = __expf(__builtin_fmaf(st[qt][kt][r], 0.125f, -mn));
          st[qt][kt][r] = p;
          bsum += p;
        }
      bsum += __shfl_xor(bsum, 16, 64);
      bsum += __shfl_xor(bsum, 32, 64);
      l[qt] = l[qt] * corr + bsum;
      m[qt] = mn;
      if (lane < 16) bb[wid][0][qt * 16 + lane] = corr;
    }
    float rc[2][4];
    #pragma unroll
    for (int qt = 0; qt < 2; ++qt)
      #pragma unroll
      for (int r = 0; r < 4; ++r) rc[qt][r] = bb[wid][0][qt * 16 + g * 4 + r];
    #pragma unroll
    for (int qt = 0; qt < 2; ++qt)
      #pragma unroll
      for (int dt = 0; dt < 4; ++dt)
        #pragma unroll
        for (int r = 0; r < 4; ++r) of[qt][dt][r] *= rc[qt][r];

    u16* P_w = (u16*)P_lds[wid];
    #pragma unroll
    for (int half = 0; half < 2; ++half) {
      #pragma unroll
      for (int qt = 0; qt < 2; ++qt)
        #pragma unroll
        for (int k4 = 0; k4 < 4; ++k4) {
          int kt = half * 4 + k4;
          u16 h0 = f2b(st[qt][kt][0]), h1 = f2b(st[qt][kt][1]);
          u16 h2 = f2b(st[qt][kt][2]), h3 = f2b(st[qt][kt][3]);
          uint2 pk = { (u32)h0 | ((u32)h1 << 16), (u32)h2 | ((u32)h3 << 16) };
          *(uint2*)&P_w[(qt * 16 + l15) * 72 + k4 * 16 + g * 4] = pk;
        }
      #pragma unroll
      for (int ks = 0; ks < 2; ++ks) {
        bf16x8 pa[2];
        #pragma unroll
        for (int qt = 0; qt < 2; ++qt)
          pa[qt] = *(const bf16x8*)&P_w[(qt * 16 + l15) * 72 + ks * 32 + g * 8];
        #pragma unroll
        for (int dt = 0; dt < 4; ++dt) {
          bf16x8 vb = *(const bf16x8*)&V_T[(dt * 16 + l15) * 136 + half * 64 + ks * 32 + g * 8];
          #pragma unroll
          for (int qt = 0; qt < 2; ++qt)
            of[qt][dt] = __builtin_amdgcn_mfma_f32_16x16x32_bf16(pa[qt], vb, of[qt][dt], 0, 0, 0);
        }
      }
    }
  }

  const int nz = (n == 0) + (n == NBLK - 1);
  #pragma unroll
  for (int qt = 0; qt < 2; ++qt) {
    float mf   = fmaxf(m[qt], sg[qt]);
    float corr = __expf(m[qt] - mf);
    float eg   = __expf(sg[qt] - mf);
    float lf   = l[qt] * corr + eg;
    if (nz) lf += (float)(nz * 128) * __expf(-mf);
    float inv = 1.f / lf;
    if (lane < 16) {
      bb[wid][0][qt * 16 + lane] = corr * inv;
      bb[wid][1][qt * 16 + lane] = eg * inv;
    }
  }
  float vgr[4];
  #pragma unroll
  for (int dt = 0; dt < 4; ++dt) vgr[dt] = Vg[dt * 16 + l15];
  #pragma unroll
  for (int qt = 0; qt < 2; ++qt)
    #pragma unroll
    for (int r = 0; r < 4; ++r) {
      float af = bb[wid][0][qt * 16 + g * 4 + r];
      float bf = bb[wid][1][qt * 16 + g * 4 + r];
      int row = q0row + qt * 16 + g * 4 + r;
      u16* dst = attnb + (rb + row) * 512 + h * 64;
      #pragma unroll
      for (int dt = 0; dt < 4; ++dt)
        dst[dt * 16 + l15] = f2b(of[qt][dt][r] * af + bf * vgr[dt]);
    }
}

extern "C" void kernel_launch(void* const* d_in, const int* in_sizes, int n_in,
                              void* d_out, int out_size, void* d_ws, size_t ws_size,
                              hipStream_t stream) {
  (void)in_sizes; (void)n_in; (void)out_size; (void)ws_size;
  const float* x  = (const float*)d_in[0];
  const float* Wq = (const float*)d_in[1];
  const float* Wk = (const float*)d_in[2];
  const float* Wv = (const float*)d_in[3];
  const float* Wo = (const float*)d_in[4];
  const float* bo = (const float*)d_in[5];
  float* out = (float*)d_out;

  char* ws = (char*)d_ws;
  u16* qkv   = (u16*)ws;
  u16* xb    = (u16*)(ws + 50337792);
  u16* attnb = (u16*)(ws + 50337792);
  u16* WoT   = (u16*)(ws + 67117056);
  u16* WqkvT = (u16*)d_out;                              // scratch; dead before gemm2
  float* gbuf = (float*)((char*)d_out + (4 << 20));      // 33 KB partials

  dim3 blk(256);
  convx<<<dim3(8193), blk, 0, stream>>>(x, xb);
  transposeW<<<dim3(24, 16), blk, 0, stream>>>(Wq, Wk, Wv, 512, WqkvT, 1024);
  gemm_bf<false><<<dim3(129 * 12), blk, 0, stream>>>(xb, WqkvT, qkv, nullptr, MROWS, 1024, 129, 12, 1536);
  transposeW<<<dim3(16, 8), blk, 0, stream>>>(Wo, Wo, Wo, 1024, WoT, 512);
  gsplit<<<dim3(256), blk, 0, stream>>>(qkv, gbuf);
  gmerge<<<dim3(16), dim3(64), 0, stream>>>(gbuf, attnb);
  local_attn_mfma<<<dim3(1024), blk, 0, stream>>>(qkv, attnb);
  gemm_bf<true><<<dim3(129 * 8), blk, 0, stream>>>(attnb, WoT, out, bo, MROWS, 512, 129, 8, 1024);
}

// Round 5
// 217.706 us; speedup vs baseline: 9.4158x; 1.0458x over previous
//
#include <hip/hip_runtime.h>
#include <hip/hip_bf16.h>

#define T_TOK 8193
#define MROWS 16386        // B*T
#define NBLK  64
#define GCH   16           // global-attn chunks per (b,h)
#define GCS   513          // chunk size (16*513 >= 8193)

typedef __attribute__((ext_vector_type(8))) short bf16x8;
typedef __attribute__((ext_vector_type(4))) float f32x4;
typedef unsigned short u16;
typedef unsigned int   u32;

__device__ __forceinline__ float blo(u32 u){ return __uint_as_float(u << 16); }
__device__ __forceinline__ float bhi(u32 u){ return __uint_as_float(u & 0xffff0000u); }
__device__ __forceinline__ u16 f2b(float f){
  u32 u = __float_as_uint(f);
  u = (u + 0x7fffu + ((u >> 16) & 1u)) >> 16;
  return (u16)u;
}
__device__ __forceinline__ float b2f(u16 v){ return __uint_as_float(((u32)v) << 16); }

#define GLDS16(gsrc, ldst) \
  __builtin_amdgcn_global_load_lds((const __attribute__((address_space(1))) void*)(gsrc), \
                                   (__attribute__((address_space(3))) void*)(ldst), 16, 0, 0)

// ---------------- x -> bf16 ----------------
__global__ __launch_bounds__(256)
void convx(const float* __restrict__ x, u16* __restrict__ xb)
{
  const size_t i = (size_t)blockIdx.x * 256 + threadIdx.x;
  const float4* p = (const float4*)x + i * 2;
  float4 a = p[0], b = p[1];
  uint4 st;
  st.x = (u32)f2b(a.x) | ((u32)f2b(a.y) << 16);
  st.y = (u32)f2b(a.z) | ((u32)f2b(a.w) << 16);
  st.z = (u32)f2b(b.x) | ((u32)f2b(b.y) << 16);
  st.w = (u32)f2b(b.z) | ((u32)f2b(b.w) << 16);
  *(uint4*)(xb + i * 8) = st;
}

// ---------------- W [K][N] fp32 (up to 3 parts) -> W^T [N][K] bf16 ----------------
__global__ __launch_bounds__(256)
void transposeW(const float* __restrict__ B0, const float* __restrict__ B1,
                const float* __restrict__ B2, int bpart,
                u16* __restrict__ outT, int K)
{
  __shared__ float tile[64][65];
  const int n0 = blockIdx.x * 64;
  const int k0 = blockIdx.y * 64;
  const int tx = threadIdx.x & 63;
  const int ty = threadIdx.x >> 6;
  const int part = n0 / bpart;
  const float* Bm = part == 0 ? B0 : (part == 1 ? B1 : B2);
  const int bn = n0 - part * bpart;
  #pragma unroll
  for (int i = 0; i < 16; ++i) {
    int k = i * 4 + ty;
    tile[tx][k] = Bm[(size_t)(k0 + k) * bpart + bn + tx];
  }
  __syncthreads();
  #pragma unroll
  for (int i = 0; i < 16; ++i) {
    int r = i * 4 + ty;
    outT[(size_t)(n0 + r) * K + k0 + tx] = f2b(tile[r][tx]);
  }
}

// ---------------- GEMM: C[M x N] = A[M x K] * BT[N x K]^T ----------------
// m97 staging (global_load_lds w16) + depth-2 3-buffer pipeline with counted
// vmcnt (T4) + XOR chunk swizzle (T2 via pre-swizzled source, m173):
//   LDS chunk (row,q) holds global chunk (row, q ^ ((row>>1)&3)); frag reads
//   use the same involution -> 16-lane groups spread over 8 (half,quad) bank
//   groups = 2-way = free. Raw s_barrier + asm vmcnt keeps loads in flight
//   across two MFMA phases (never drains to 0 mid-loop).
template<bool OUT_F32>
__global__ __launch_bounds__(256)
void gemm_bf(const u16* __restrict__ A, const u16* __restrict__ BT,
             void* __restrict__ Cp, const float* __restrict__ bias,
             int M, int K, int ntm, int ntn, int ldc)
{
  __shared__ u16 As[3][128 * 32];
  __shared__ u16 Bs[3][128 * 32];
  const int tid  = threadIdx.x;
  const int lane = tid & 63;
  const int wid  = tid >> 6;
  const int l15  = lane & 15;
  const int g    = lane >> 4;
  const int wr   = (wid >> 1) * 64;
  const int wc   = (wid & 1) * 64;

  const int nwg  = gridDim.x;
  const int orig = blockIdx.x;
  const int q8 = nwg >> 3, r8 = nwg & 7;
  const int xcd = orig & 7, loc = orig >> 3;
  const int wg = (xcd < r8 ? xcd * (q8 + 1) : r8 * (q8 + 1) + (xcd - r8) * q8) + loc;
  // A-strip grouped order (L2 locality)
  const int GT  = 8;
  const int gsz = GT * ntn;
  const int tg  = wg / gsz;
  const int rem = wg - tg * gsz;
  const int gt  = (ntm - tg * GT < GT) ? (ntm - tg * GT) : GT;
  const int tn  = rem / gt;
  const int tml = rem - tn * gt;
  const int tm  = tg * GT + tml;
  const int bm0 = tm * 128, bn0 = tn * 128;

  f32x4 acc[4][4];
  #pragma unroll
  for (int i = 0; i < 4; ++i)
    #pragma unroll
    for (int j = 0; j < 4; ++j) { f32x4 z = {0.f,0.f,0.f,0.f}; acc[i][j] = z; }

  // staging: 512 x 16B chunks per tile; chunk c -> (row=c>>2, q=c&3);
  // source chunk pre-swizzled: srcq = q ^ ((row>>1)&3)  (involution)
  const int srcq = ((tid & 3) ^ ((tid >> 3) & 3)) * 8;
  int ar0 = bm0 + (tid >> 2);      if (ar0 >= M) ar0 = M - 1;
  int ar1 = bm0 + 64 + (tid >> 2); if (ar1 >= M) ar1 = M - 1;
  const u16* Ag0 = A + (size_t)ar0 * K + srcq;
  const u16* Ag1 = A + (size_t)ar1 * K + srcq;
  const u16* Bg0 = BT + (size_t)(bn0 + (tid >> 2)) * K + srcq;
  const u16* Bg1 = BT + (size_t)(bn0 + 64 + (tid >> 2)) * K + srcq;
  const int ld0 = tid * 8, ld1 = tid * 8 + 2048;

#define STAGE_T(bf, kt) do { \
    GLDS16(Ag0 + (kt), &As[bf][ld0]); \
    GLDS16(Ag1 + (kt), &As[bf][ld1]); \
    GLDS16(Bg0 + (kt), &Bs[bf][ld0]); \
    GLDS16(Bg1 + (kt), &Bs[bf][ld1]); \
  } while (0)

  const int Tst = K >> 5;
  STAGE_T(0, 0);
  STAGE_T(1, 32);

  // frag-read chunk swizzle: same involution, row-dependent part is (l15>>1)&3
  const int qa = (g ^ ((l15 >> 1) & 3)) * 8;

  int cur = 0;
  for (int t = 0; t < Tst; ++t) {
    __builtin_amdgcn_s_barrier();              // all waves done reading buf (t-1)
    int nb = cur + 2; if (nb >= 3) nb -= 3;
    if (t + 2 < Tst) {
      STAGE_T(nb, (t + 2) * 32);
      asm volatile("s_waitcnt vmcnt(8)" ::: "memory");   // cur's loads done
    } else if (t + 2 == Tst) {
      asm volatile("s_waitcnt vmcnt(4)" ::: "memory");
    } else {
      asm volatile("s_waitcnt vmcnt(0)" ::: "memory");
    }
    __builtin_amdgcn_s_barrier();              // cur visible to all
    __builtin_amdgcn_sched_barrier(0);         // pin ds_reads below barrier
    bf16x8 af[4], bfr[4];
    #pragma unroll
    for (int mi = 0; mi < 4; ++mi)
      af[mi] = *(const bf16x8*)&As[cur][(wr + mi * 16 + l15) * 32 + qa];
    #pragma unroll
    for (int ni = 0; ni < 4; ++ni)
      bfr[ni] = *(const bf16x8*)&Bs[cur][(wc + ni * 16 + l15) * 32 + qa];
    #pragma unroll
    for (int mi = 0; mi < 4; ++mi)
      #pragma unroll
      for (int ni = 0; ni < 4; ++ni)
        acc[mi][ni] = __builtin_amdgcn_mfma_f32_16x16x32_bf16(af[mi], bfr[ni], acc[mi][ni], 0, 0, 0);
    cur = (cur + 1 == 3) ? 0 : cur + 1;
  }
#undef STAGE_T

  const int r0 = g * 4;
  #pragma unroll
  for (int mi = 0; mi < 4; ++mi) {
    #pragma unroll
    for (int r = 0; r < 4; ++r) {
      int grow = bm0 + wr + mi * 16 + r0 + r;
      if (grow >= M) continue;
      #pragma unroll
      for (int ni = 0; ni < 4; ++ni) {
        int gcol  = bn0 + wc + ni * 16 + l15;
        float val = acc[mi][ni][r];
        if (OUT_F32) ((float*)Cp)[(size_t)grow * ldc + gcol] = val + bias[gcol];
        else         ((u16*)Cp)[(size_t)grow * ldc + gcol]   = f2b(val);
      }
    }
  }
}

// ---------------- global-token attention, split into chunks ----------------
__global__ __launch_bounds__(256)
void gsplit(const u16* __restrict__ qkv, float* __restrict__ gbuf)
{
  const int c   = blockIdx.x & 15;
  const int h   = (blockIdx.x >> 4) & 7;
  const int b   = blockIdx.x >> 7;
  const int tid = threadIdx.x;
  const int lane = tid & 63;
  const int wid  = tid >> 6;
  const int t0 = c * GCS;
  const int t1 = (t0 + GCS < T_TOK) ? (t0 + GCS) : T_TOK;
  const int nt = t1 - t0;

  __shared__ float sc[GCS];
  __shared__ float q0s[64];
  __shared__ float wredm[4], wreds[4];
  __shared__ float psum[4][64];

  const size_t base = (size_t)b * T_TOK * 1536;
  if (tid < 32) {
    u32 u = ((const u32*)(qkv + base + h * 64))[tid];
    q0s[2 * tid] = blo(u); q0s[2 * tid + 1] = bhi(u);
  }
  __syncthreads();

  float lmax = -INFINITY;
  for (int tt = tid; tt < nt; tt += 256) {
    const uint4* kp = (const uint4*)(qkv + base + (size_t)(t0 + tt) * 1536 + 512 + h * 64);
    float a = 0.f;
    #pragma unroll
    for (int q8 = 0; q8 < 8; ++q8) {
      uint4 kk = kp[q8];
      a += q0s[q8*8+0]*blo(kk.x) + q0s[q8*8+1]*bhi(kk.x)
         + q0s[q8*8+2]*blo(kk.y) + q0s[q8*8+3]*bhi(kk.y)
         + q0s[q8*8+4]*blo(kk.z) + q0s[q8*8+5]*bhi(kk.z)
         + q0s[q8*8+6]*blo(kk.w) + q0s[q8*8+7]*bhi(kk.w);
    }
    a *= 0.125f;
    sc[tt] = a;
    lmax = fmaxf(lmax, a);
  }
  for (int o = 32; o; o >>= 1) lmax = fmaxf(lmax, __shfl_xor(lmax, o, 64));
  if (lane == 0) wredm[wid] = lmax;
  __syncthreads();
  float bmax = fmaxf(fmaxf(wredm[0], wredm[1]), fmaxf(wredm[2], wredm[3]));
  float lsum = 0.f;
  for (int tt = tid; tt < nt; tt += 256) {
    float e = __expf(sc[tt] - bmax);
    sc[tt] = e;
    lsum += e;
  }
  for (int o = 32; o; o >>= 1) lsum += __shfl_xor(lsum, o, 64);
  if (lane == 0) wreds[wid] = lsum;
  __syncthreads();
  float bsum = wreds[0] + wreds[1] + wreds[2] + wreds[3];

  const int g = tid >> 6;
  const int d = tid & 63;
  float acc = 0.f;
  for (int tt = g; tt < nt; tt += 4)
    acc += sc[tt] * b2f(qkv[base + (size_t)(t0 + tt) * 1536 + 1024 + h * 64 + d]);
  psum[g][d] = acc;
  __syncthreads();

  float* rec = gbuf + ((size_t)(b * 8 + h) * GCH + c) * 66;
  if (tid < 64)
    rec[2 + tid] = psum[0][tid] + psum[1][tid] + psum[2][tid] + psum[3][tid];
  if (tid == 64) { rec[0] = bmax; rec[1] = bsum; }
}

__global__ __launch_bounds__(64)
void gmerge(const float* __restrict__ gbuf, u16* __restrict__ attnb)
{
  const int bh = blockIdx.x;
  const int d  = threadIdx.x;
  const float* recs = gbuf + (size_t)bh * GCH * 66;
  float m = -INFINITY;
  #pragma unroll
  for (int c = 0; c < GCH; ++c) m = fmaxf(m, recs[c * 66]);
  float l = 0.f, o = 0.f;
  #pragma unroll
  for (int c = 0; c < GCH; ++c) {
    float e = __expf(recs[c * 66] - m);
    l += recs[c * 66 + 1] * e;
    o += recs[c * 66 + 2 + d] * e;
  }
  const int b = bh >> 3, h = bh & 7;
  attnb[(size_t)b * T_TOK * 512 + h * 64 + d] = f2b(o / l);
}

// ---------------- block-local attention: MFMA flash, 1 workgroup per (b,h,n) ----------------
__global__ __launch_bounds__(256)
void local_attn_mfma(const u16* __restrict__ qkv, u16* __restrict__ attnb)
{
  const int bid = blockIdx.x;
  const int n = bid & 63;
  const int h = (bid >> 6) & 7;
  const int b = bid >> 9;
  const int tid  = threadIdx.x;
  const int lane = tid & 63;
  const int wid  = tid >> 6;
  const int l15  = lane & 15;
  const int g    = lane >> 4;

  __shared__ u16 K_lds[128 * 72];
  __shared__ u16 V_T[64 * 136];
  __shared__ u16 P_lds[4][32 * 72];
  __shared__ float bb[4][2][32];
  __shared__ float Kg[64], Vg[64];

  const size_t rb = (size_t)b * T_TOK;
  if (tid < 64) {
    Kg[tid] = b2f(qkv[rb * 1536 + 512 + h * 64 + tid]);
    Vg[tid] = b2f(qkv[rb * 1536 + 1024 + h * 64 + tid]);
  }

  const int q0row = 1 + n * 128 + wid * 32;
  bf16x8 qf[2][2];
  #pragma unroll
  for (int qt = 0; qt < 2; ++qt)
    #pragma unroll
    for (int kk = 0; kk < 2; ++kk)
      qf[qt][kk] = *(const bf16x8*)(qkv + (rb + q0row + qt * 16 + l15) * 1536 + h * 64 + kk * 32 + g * 8);

  __syncthreads();

  float sg[2];
  #pragma unroll
  for (int qt = 0; qt < 2; ++qt) {
    float part = 0.f;
    #pragma unroll
    for (int kk = 0; kk < 2; ++kk)
      #pragma unroll
      for (int i = 0; i < 8; ++i)
        part += b2f((u16)qf[qt][kk][i]) * Kg[kk * 32 + g * 8 + i];
    part += __shfl_xor(part, 16, 64);
    part += __shfl_xor(part, 32, 64);
    sg[qt] = part * 0.125f;
  }

  float m[2] = {-INFINITY, -INFINITY};
  float l[2] = {0.f, 0.f};
  f32x4 of[2][4];
  #pragma unroll
  for (int qt = 0; qt < 2; ++qt)
    #pragma unroll
    for (int dt = 0; dt < 4; ++dt) { f32x4 z = {0.f,0.f,0.f,0.f}; of[qt][dt] = z; }

  for (int dblk = 0; dblk < 3; ++dblk) {
    const int blk = n + dblk - 1;
    if (blk < 0 || blk >= NBLK) continue;
    const size_t krow0 = rb + 1 + (size_t)blk * 128;

    __syncthreads();
    #pragma unroll
    for (int it = 0; it < 4; ++it) {
      int c = it * 256 + tid;
      int key = c >> 3, oct = c & 7;
      *(uint4*)&K_lds[key * 72 + oct * 8] =
          *(const uint4*)(qkv + (krow0 + key) * 1536 + 512 + h * 64 + oct * 8);
    }
    #pragma unroll
    for (int it = 0; it < 2; ++it) {
      int c = it * 256 + tid;
      int kp2 = c & 63, oct = c >> 6;
      const u16* s0 = qkv + (krow0 + 2 * kp2) * 1536 + 1024 + h * 64 + oct * 8;
      uint4 va = *(const uint4*)s0;
      uint4 vb4 = *(const uint4*)(s0 + 1536);
      union { uint4 q; u16 hh[8]; } ua, ub;
      ua.q = va; ub.q = vb4;
      #pragma unroll
      for (int i = 0; i < 8; ++i) {
        u32 w = (u32)ua.hh[i] | ((u32)ub.hh[i] << 16);
        *(u32*)&V_T[(oct * 8 + i) * 136 + 2 * kp2] = w;
      }
    }
    __syncthreads();

    f32x4 st[2][8];
    #pragma unroll
    for (int kt = 0; kt < 8; ++kt) {
      bf16x8 kfr[2];
      #pragma unroll
      for (int kk = 0; kk < 2; ++kk)
        kfr[kk] = *(const bf16x8*)&K_lds[(kt * 16 + l15) * 72 + kk * 32 + g * 8];
      #pragma unroll
      for (int qt = 0; qt < 2; ++qt) {
        f32x4 z = {0.f,0.f,0.f,0.f};
        z = __builtin_amdgcn_mfma_f32_16x16x32_bf16(kfr[0], qf[qt][0], z, 0, 0, 0);
        z = __builtin_amdgcn_mfma_f32_16x16x32_bf16(kfr[1], qf[qt][1], z, 0, 0, 0);
        st[qt][kt] = z;
      }
    }
    #pragma unroll
    for (int qt = 0; qt < 2; ++qt) {
      float bm = -INFINITY;
      #pragma unroll
      for (int kt = 0; kt < 8; ++kt)
        #pragma unroll
        for (int r = 0; r < 4; ++r) bm = fmaxf(bm, st[qt][kt][r]);
      bm = fmaxf(bm, __shfl_xor(bm, 16, 64));
      bm = fmaxf(bm, __shfl_xor(bm, 32, 64));
      bm *= 0.125f;
      float mn = fmaxf(m[qt], bm);
      float corr = __expf(m[qt] - mn);
      float bsum = 0.f;
      #pragma unroll
      for (int kt = 0; kt < 8; ++kt)
        #pragma unroll
        for (int r = 0; r < 4; ++r) {
          float p = __expf(__builtin_fmaf(st[qt][kt][r], 0.125f, -mn));
          st[qt][kt][r] = p;
          bsum += p;
        }
      bsum += __shfl_xor(bsum, 16, 64);
      bsum += __shfl_xor(bsum, 32, 64);
      l[qt] = l[qt] * corr + bsum;
      m[qt] = mn;
      if (lane < 16) bb[wid][0][qt * 16 + lane] = corr;
    }
    float rc[2][4];
    #pragma unroll
    for (int qt = 0; qt < 2; ++qt)
      #pragma unroll
      for (int r = 0; r < 4; ++r) rc[qt][r] = bb[wid][0][qt * 16 + g * 4 + r];
    #pragma unroll
    for (int qt = 0; qt < 2; ++qt)
      #pragma unroll
      for (int dt = 0; dt < 4; ++dt)
        #pragma unroll
        for (int r = 0; r < 4; ++r) of[qt][dt][r] *= rc[qt][r];

    u16* P_w = (u16*)P_lds[wid];
    #pragma unroll
    for (int half = 0; half < 2; ++half) {
      #pragma unroll
      for (int qt = 0; qt < 2; ++qt)
        #pragma unroll
        for (int k4 = 0; k4 < 4; ++k4) {
          int kt = half * 4 + k4;
          u16 h0 = f2b(st[qt][kt][0]), h1 = f2b(st[qt][kt][1]);
          u16 h2 = f2b(st[qt][kt][2]), h3 = f2b(st[qt][kt][3]);
          uint2 pk = { (u32)h0 | ((u32)h1 << 16), (u32)h2 | ((u32)h3 << 16) };
          *(uint2*)&P_w[(qt * 16 + l15) * 72 + k4 * 16 + g * 4] = pk;
        }
      #pragma unroll
      for (int ks = 0; ks < 2; ++ks) {
        bf16x8 pa[2];
        #pragma unroll
        for (int qt = 0; qt < 2; ++qt)
          pa[qt] = *(const bf16x8*)&P_w[(qt * 16 + l15) * 72 + ks * 32 + g * 8];
        #pragma unroll
        for (int dt = 0; dt < 4; ++dt) {
          bf16x8 vb = *(const bf16x8*)&V_T[(dt * 16 + l15) * 136 + half * 64 + ks * 32 + g * 8];
          #pragma unroll
          for (int qt = 0; qt < 2; ++qt)
            of[qt][dt] = __builtin_amdgcn_mfma_f32_16x16x32_bf16(pa[qt], vb, of[qt][dt], 0, 0, 0);
        }
      }
    }
  }

  const int nz = (n == 0) + (n == NBLK - 1);
  #pragma unroll
  for (int qt = 0; qt < 2; ++qt) {
    float mf   = fmaxf(m[qt], sg[qt]);
    float corr = __expf(m[qt] - mf);
    float eg   = __expf(sg[qt] - mf);
    float lf   = l[qt] * corr + eg;
    if (nz) lf += (float)(nz * 128) * __expf(-mf);
    float inv = 1.f / lf;
    if (lane < 16) {
      bb[wid][0][qt * 16 + lane] = corr * inv;
      bb[wid][1][qt * 16 + lane] = eg * inv;
    }
  }
  float vgr[4];
  #pragma unroll
  for (int dt = 0; dt < 4; ++dt) vgr[dt] = Vg[dt * 16 + l15];
  #pragma unroll
  for (int qt = 0; qt < 2; ++qt)
    #pragma unroll
    for (int r = 0; r < 4; ++r) {
      float af = bb[wid][0][qt * 16 + g * 4 + r];
      float bf = bb[wid][1][qt * 16 + g * 4 + r];
      int row = q0row + qt * 16 + g * 4 + r;
      u16* dst = attnb + (rb + row) * 512 + h * 64;
      #pragma unroll
      for (int dt = 0; dt < 4; ++dt)
        dst[dt * 16 + l15] = f2b(of[qt][dt][r] * af + bf * vgr[dt]);
    }
}

extern "C" void kernel_launch(void* const* d_in, const int* in_sizes, int n_in,
                              void* d_out, int out_size, void* d_ws, size_t ws_size,
                              hipStream_t stream) {
  (void)in_sizes; (void)n_in; (void)out_size; (void)ws_size;
  const float* x  = (const float*)d_in[0];
  const float* Wq = (const float*)d_in[1];
  const float* Wk = (const float*)d_in[2];
  const float* Wv = (const float*)d_in[3];
  const float* Wo = (const float*)d_in[4];
  const float* bo = (const float*)d_in[5];
  float* out = (float*)d_out;

  char* ws = (char*)d_ws;
  u16* qkv   = (u16*)ws;
  u16* xb    = (u16*)(ws + 50337792);
  u16* attnb = (u16*)(ws + 50337792);
  u16* WoT   = (u16*)(ws + 67117056);
  u16* WqkvT = (u16*)d_out;                              // scratch; dead before gemm2
  float* gbuf = (float*)((char*)d_out + (4 << 20));      // 33 KB partials

  dim3 blk(256);
  convx<<<dim3(8193), blk, 0, stream>>>(x, xb);
  transposeW<<<dim3(24, 16), blk, 0, stream>>>(Wq, Wk, Wv, 512, WqkvT, 1024);
  gemm_bf<false><<<dim3(129 * 12), blk, 0, stream>>>(xb, WqkvT, qkv, nullptr, MROWS, 1024, 129, 12, 1536);
  transposeW<<<dim3(16, 8), blk, 0, stream>>>(Wo, Wo, Wo, 1024, WoT, 512);
  gsplit<<<dim3(256), blk, 0, stream>>>(qkv, gbuf);
  gmerge<<<dim3(16), dim3(64), 0, stream>>>(gbuf, attnb);
  local_attn_mfma<<<dim3(1024), blk, 0, stream>>>(qkv, attnb);
  gemm_bf<true><<<dim3(129 * 8), blk, 0, stream>>>(attnb, WoT, out, bo, MROWS, 512, 129, 8, 1024);
}

// Round 6
// 205.071 us; speedup vs baseline: 9.9959x; 1.0616x over previous
//
#include <hip/hip_runtime.h>
#include <hip/hip_bf16.h>

#define T_TOK 8193
#define MROWS 16386        // B*T
#define NBLK  64
#define GCH   16           // global-attn chunks per (b,h)
#define GCS   513          // chunk size (16*513 >= 8193)

typedef __attribute__((ext_vector_type(8))) short bf16x8;
typedef __attribute__((ext_vector_type(4))) float f32x4;
typedef unsigned short u16;
typedef unsigned int   u32;

__device__ __forceinline__ float blo(u32 u){ return __uint_as_float(u << 16); }
__device__ __forceinline__ float bhi(u32 u){ return __uint_as_float(u & 0xffff0000u); }
__device__ __forceinline__ u16 f2b(float f){
  u32 u = __float_as_uint(f);
  u = (u + 0x7fffu + ((u >> 16) & 1u)) >> 16;
  return (u16)u;
}
__device__ __forceinline__ float b2f(u16 v){ return __uint_as_float(((u32)v) << 16); }

#define GLDS16(gsrc, ldst) \
  __builtin_amdgcn_global_load_lds((const __attribute__((address_space(1))) void*)(gsrc), \
                                   (__attribute__((address_space(3))) void*)(ldst), 16, 0, 0)

// ---------------- x -> bf16 ----------------
__global__ __launch_bounds__(256)
void convx(const float* __restrict__ x, u16* __restrict__ xb)
{
  const size_t i = (size_t)blockIdx.x * 256 + threadIdx.x;
  const float4* p = (const float4*)x + i * 2;
  float4 a = p[0], b = p[1];
  uint4 st;
  st.x = (u32)f2b(a.x) | ((u32)f2b(a.y) << 16);
  st.y = (u32)f2b(a.z) | ((u32)f2b(a.w) << 16);
  st.z = (u32)f2b(b.x) | ((u32)f2b(b.y) << 16);
  st.w = (u32)f2b(b.z) | ((u32)f2b(b.w) << 16);
  *(uint4*)(xb + i * 8) = st;
}

// ---------------- W [K][N] fp32 (up to 3 parts) -> W^T [N][K] bf16 ----------------
__global__ __launch_bounds__(256)
void transposeW(const float* __restrict__ B0, const float* __restrict__ B1,
                const float* __restrict__ B2, int bpart,
                u16* __restrict__ outT, int K)
{
  __shared__ float tile[64][65];
  const int n0 = blockIdx.x * 64;
  const int k0 = blockIdx.y * 64;
  const int tx = threadIdx.x & 63;
  const int ty = threadIdx.x >> 6;
  const int part = n0 / bpart;
  const float* Bm = part == 0 ? B0 : (part == 1 ? B1 : B2);
  const int bn = n0 - part * bpart;
  #pragma unroll
  for (int i = 0; i < 16; ++i) {
    int k = i * 4 + ty;
    tile[tx][k] = Bm[(size_t)(k0 + k) * bpart + bn + tx];
  }
  __syncthreads();
  #pragma unroll
  for (int i = 0; i < 16; ++i) {
    int r = i * 4 + ty;
    outT[(size_t)(n0 + r) * K + k0 + tx] = f2b(tile[r][tx]);
  }
}

// ---------------- GEMM: 256x256 tile, 8-phase schedule (T2+T3+T4+T5) ----------------
// 512 threads = 8 waves (2M x 4N). BK=64, 2 K-tiles per iteration, 2 LDS buffers.
// LDS layout: lds[buf][A=0/B=1][half][128][64] u16 = 128 KiB total.
// Chunk swizzle (both sides): LDS chunk c of row r holds global chunk c^(r&7).
// Per phase: {ds_read frags | stage 1 half-tile (2x global_load_lds w16)} ->
// barrier -> setprio(1) -> 16 MFMA -> setprio(0) -> [vmcnt(4) @P4/P8] -> barrier.
// Stage schedule (iteration computes tiles t=2i from buf0, t+1 from buf1):
//   P1: A(t+1)h0->buf1A  P2: A(t+1)h1  P3: B(t+2)h0->buf0B  P4: B(t+2)h1 +vmcnt(4)
//   P5: A(t+2)h0->buf0A  P6: A(t+2)h1  P7: B(t+3)h0->buf1B  P8: B(t+3)h1 +vmcnt(4)
// Every region's stage-issue is >=1 barrier-rendezvous after its last reader.
template<bool OUT_F32>
__global__ __launch_bounds__(512, 2)
void gemm8(const u16* __restrict__ A, const u16* __restrict__ BT,
           void* __restrict__ Cp, const float* __restrict__ bias,
           int M, int K, int ntm, int ntn, int ldc)
{
  __shared__ u16 lds[65536];   // [buf][ab][half] x 8192 u16
  const int tid  = threadIdx.x;
  const int lane = tid & 63;
  const int wid  = tid >> 6;
  const int l15  = lane & 15;
  const int g    = lane >> 4;
  const int wrh  = wid >> 2;            // A half (0/1): rows wrh*128..+127
  const int wc   = (wid & 3) * 64;      // B col base 0..192
  const int bh   = (wid & 3) >> 1;      // B half
  const int wcl  = (wid & 1) * 64;      // B row base within half

  // bijective XCD swizzle + A-strip grouped order (GT tm-tiles per group)
  const int nwg  = gridDim.x;
  const int orig = blockIdx.x;
  const int q8 = nwg >> 3, r8 = nwg & 7;
  const int xcd = orig & 7, loc = orig >> 3;
  const int wg = (xcd < r8 ? xcd * (q8 + 1) : r8 * (q8 + 1) + (xcd - r8) * q8) + loc;
  const int GT  = 4;
  const int gsz = GT * ntn;
  const int tg  = wg / gsz;
  const int rem = wg - tg * gsz;
  const int gt  = (ntm - tg * GT < GT) ? (ntm - tg * GT) : GT;
  const int tn  = rem / gt;
  const int tml = rem - tn * gt;
  const int bm0 = (tg * GT + tml) * 256;
  const int bn0 = tn * 256;

  f32x4 acc[8][4];
  #pragma unroll
  for (int i = 0; i < 8; ++i)
    #pragma unroll
    for (int j = 0; j < 4; ++j) { f32x4 z = {0.f,0.f,0.f,0.f}; acc[i][j] = z; }

  // staging addresses: thread -> (row r = tid>>3 within 64-row block, chunk ch = tid&7)
  const int rr  = tid >> 3;
  const int gq  = (((tid & 7) ^ (rr & 7))) * 8;   // pre-swizzled source chunk
  const int ldst0 = tid * 8;                      // linear LDS dest (u16)
  u32 aOff[2][2], bOff[2][2];
  #pragma unroll
  for (int h = 0; h < 2; ++h)
    #pragma unroll
    for (int j = 0; j < 2; ++j) {
      int ar = bm0 + h * 128 + j * 64 + rr; if (ar >= M) ar = M - 1;
      aOff[h][j] = (u32)ar * (u32)K + gq;
      bOff[h][j] = (u32)(bn0 + h * 128 + j * 64 + rr) * (u32)K + gq;
    }

#define LBASE(BUF, AB, H) (((((BUF)*2 + (AB))*2 + (H)) * 8192))
#define STAGE_A(BUF, H, KO) do { \
    GLDS16(A + aOff[H][0] + (KO), &lds[LBASE(BUF,0,H) + ldst0]); \
    GLDS16(A + aOff[H][1] + (KO), &lds[LBASE(BUF,0,H) + 4096 + ldst0]); \
  } while (0)
#define STAGE_B(BUF, H, KO) do { \
    GLDS16(BT + bOff[H][0] + (KO), &lds[LBASE(BUF,1,H) + ldst0]); \
    GLDS16(BT + bOff[H][1] + (KO), &lds[LBASE(BUF,1,H) + 4096 + ldst0]); \
  } while (0)

  // frag-read chunk swizzle (row&7 == l15&7 since row bases are 16-multiples)
  int ca[2];
  ca[0] = ((0 * 4 + g) ^ (l15 & 7)) * 8;
  ca[1] = ((1 * 4 + g) ^ (l15 & 7)) * 8;

  bf16x8 bf[4][2];

#define PHASE(BUF, P, STAGE_STMT, DOVM, VMLAST) do { \
    bf16x8 af[2][2]; \
    if ((P) == 0) { \
      _Pragma("unroll") \
      for (int ni = 0; ni < 4; ++ni) { \
        bf[ni][0] = *(const bf16x8*)&lds[LBASE(BUF,1,bh) + (wcl + ni*16 + l15)*64 + ca[0]]; \
        bf[ni][1] = *(const bf16x8*)&lds[LBASE(BUF,1,bh) + (wcl + ni*16 + l15)*64 + ca[1]]; \
      } \
    } \
    _Pragma("unroll") \
    for (int mi = 0; mi < 2; ++mi) { \
      af[mi][0] = *(const bf16x8*)&lds[LBASE(BUF,0,wrh) + (((P)*2+mi)*16 + l15)*64 + ca[0]]; \
      af[mi][1] = *(const bf16x8*)&lds[LBASE(BUF,0,wrh) + (((P)*2+mi)*16 + l15)*64 + ca[1]]; \
    } \
    STAGE_STMT; \
    __builtin_amdgcn_s_barrier(); \
    __builtin_amdgcn_s_setprio(1); \
    _Pragma("unroll") \
    for (int mi = 0; mi < 2; ++mi) \
      _Pragma("unroll") \
      for (int ni = 0; ni < 4; ++ni) { \
        acc[(P)*2+mi][ni] = __builtin_amdgcn_mfma_f32_16x16x32_bf16(af[mi][0], bf[ni][0], acc[(P)*2+mi][ni], 0, 0, 0); \
        acc[(P)*2+mi][ni] = __builtin_amdgcn_mfma_f32_16x16x32_bf16(af[mi][1], bf[ni][1], acc[(P)*2+mi][ni], 0, 0, 0); \
      } \
    __builtin_amdgcn_s_setprio(0); \
    if (DOVM) { \
      if (VMLAST) asm volatile("s_waitcnt vmcnt(0)" ::: "memory"); \
      else        asm volatile("s_waitcnt vmcnt(4)" ::: "memory"); \
    } \
    __builtin_amdgcn_s_barrier(); \
  } while (0)

  // ---- prologue: B(0), A(0), B(1); keep B(1) in flight ----
  STAGE_B(0, 0, 0);  STAGE_B(0, 1, 0);
  STAGE_A(0, 0, 0);  STAGE_A(0, 1, 0);
  STAGE_B(1, 0, 64); STAGE_B(1, 1, 64);
  asm volatile("s_waitcnt vmcnt(4)" ::: "memory");
  __builtin_amdgcn_s_barrier();

  const int nit = K >> 7;      // K / 128 (2 tiles of 64 per iteration)
  for (int it = 0; it < nit; ++it) {
    const int t2 = it << 7;    // u16 k-offset of tile t
    const bool ls = (it == nit - 1);
    PHASE(0, 0, STAGE_A(1, 0, t2 + 64), false, false);
    PHASE(0, 1, STAGE_A(1, 1, t2 + 64), false, false);
    PHASE(0, 2, if (!ls) STAGE_B(0, 0, t2 + 128), false, false);
    PHASE(0, 3, if (!ls) STAGE_B(0, 1, t2 + 128), true, ls);
    PHASE(1, 0, if (!ls) STAGE_A(0, 0, t2 + 128), false, false);
    PHASE(1, 1, if (!ls) STAGE_A(0, 1, t2 + 128), false, false);
    PHASE(1, 2, if (!ls) STAGE_B(1, 0, t2 + 192), false, false);
    PHASE(1, 3, if (!ls) STAGE_B(1, 1, t2 + 192), true, ls);
  }
#undef PHASE
#undef STAGE_A
#undef STAGE_B
#undef LBASE

  // ---- epilogue ----
  #pragma unroll
  for (int mi = 0; mi < 8; ++mi) {
    #pragma unroll
    for (int r = 0; r < 4; ++r) {
      int grow = bm0 + wrh * 128 + mi * 16 + g * 4 + r;
      if (grow >= M) continue;
      #pragma unroll
      for (int ni = 0; ni < 4; ++ni) {
        int gcol  = bn0 + wc + ni * 16 + l15;
        float val = acc[mi][ni][r];
        if (OUT_F32) ((float*)Cp)[(size_t)grow * ldc + gcol] = val + bias[gcol];
        else         ((u16*)Cp)[(size_t)grow * ldc + gcol]   = f2b(val);
      }
    }
  }
}

// ---------------- global-token attention, split into chunks ----------------
__global__ __launch_bounds__(256)
void gsplit(const u16* __restrict__ qkv, float* __restrict__ gbuf)
{
  const int c   = blockIdx.x & 15;
  const int h   = (blockIdx.x >> 4) & 7;
  const int b   = blockIdx.x >> 7;
  const int tid = threadIdx.x;
  const int lane = tid & 63;
  const int wid  = tid >> 6;
  const int t0 = c * GCS;
  const int t1 = (t0 + GCS < T_TOK) ? (t0 + GCS) : T_TOK;
  const int nt = t1 - t0;

  __shared__ float sc[GCS];
  __shared__ float q0s[64];
  __shared__ float wredm[4], wreds[4];
  __shared__ float psum[4][64];

  const size_t base = (size_t)b * T_TOK * 1536;
  if (tid < 32) {
    u32 u = ((const u32*)(qkv + base + h * 64))[tid];
    q0s[2 * tid] = blo(u); q0s[2 * tid + 1] = bhi(u);
  }
  __syncthreads();

  float lmax = -INFINITY;
  for (int tt = tid; tt < nt; tt += 256) {
    const uint4* kp = (const uint4*)(qkv + base + (size_t)(t0 + tt) * 1536 + 512 + h * 64);
    float a = 0.f;
    #pragma unroll
    for (int q8 = 0; q8 < 8; ++q8) {
      uint4 kk = kp[q8];
      a += q0s[q8*8+0]*blo(kk.x) + q0s[q8*8+1]*bhi(kk.x)
         + q0s[q8*8+2]*blo(kk.y) + q0s[q8*8+3]*bhi(kk.y)
         + q0s[q8*8+4]*blo(kk.z) + q0s[q8*8+5]*bhi(kk.z)
         + q0s[q8*8+6]*blo(kk.w) + q0s[q8*8+7]*bhi(kk.w);
    }
    a *= 0.125f;
    sc[tt] = a;
    lmax = fmaxf(lmax, a);
  }
  for (int o = 32; o; o >>= 1) lmax = fmaxf(lmax, __shfl_xor(lmax, o, 64));
  if (lane == 0) wredm[wid] = lmax;
  __syncthreads();
  float bmax = fmaxf(fmaxf(wredm[0], wredm[1]), fmaxf(wredm[2], wredm[3]));
  float lsum = 0.f;
  for (int tt = tid; tt < nt; tt += 256) {
    float e = __expf(sc[tt] - bmax);
    sc[tt] = e;
    lsum += e;
  }
  for (int o = 32; o; o >>= 1) lsum += __shfl_xor(lsum, o, 64);
  if (lane == 0) wreds[wid] = lsum;
  __syncthreads();
  float bsum = wreds[0] + wreds[1] + wreds[2] + wreds[3];

  const int g = tid >> 6;
  const int d = tid & 63;
  float acc = 0.f;
  for (int tt = g; tt < nt; tt += 4)
    acc += sc[tt] * b2f(qkv[base + (size_t)(t0 + tt) * 1536 + 1024 + h * 64 + d]);
  psum[g][d] = acc;
  __syncthreads();

  float* rec = gbuf + ((size_t)(b * 8 + h) * GCH + c) * 66;
  if (tid < 64)
    rec[2 + tid] = psum[0][tid] + psum[1][tid] + psum[2][tid] + psum[3][tid];
  if (tid == 64) { rec[0] = bmax; rec[1] = bsum; }
}

__global__ __launch_bounds__(64)
void gmerge(const float* __restrict__ gbuf, u16* __restrict__ attnb)
{
  const int bh = blockIdx.x;
  const int d  = threadIdx.x;
  const float* recs = gbuf + (size_t)bh * GCH * 66;
  float m = -INFINITY;
  #pragma unroll
  for (int c = 0; c < GCH; ++c) m = fmaxf(m, recs[c * 66]);
  float l = 0.f, o = 0.f;
  #pragma unroll
  for (int c = 0; c < GCH; ++c) {
    float e = __expf(recs[c * 66] - m);
    l += recs[c * 66 + 1] * e;
    o += recs[c * 66 + 2 + d] * e;
  }
  const int b = bh >> 3, h = bh & 7;
  attnb[(size_t)b * T_TOK * 512 + h * 64 + d] = f2b(o / l);
}

// ---------------- block-local attention: MFMA flash, 1 workgroup per (b,h,n) ----------------
__global__ __launch_bounds__(256)
void local_attn_mfma(const u16* __restrict__ qkv, u16* __restrict__ attnb)
{
  const int bid = blockIdx.x;
  const int n = bid & 63;
  const int h = (bid >> 6) & 7;
  const int b = bid >> 9;
  const int tid  = threadIdx.x;
  const int lane = tid & 63;
  const int wid  = tid >> 6;
  const int l15  = lane & 15;
  const int g    = lane >> 4;

  __shared__ u16 K_lds[128 * 72];
  __shared__ u16 V_T[64 * 136];
  __shared__ u16 P_lds[4][32 * 72];
  __shared__ float bb[4][2][32];
  __shared__ float Kg[64], Vg[64];

  const size_t rb = (size_t)b * T_TOK;
  if (tid < 64) {
    Kg[tid] = b2f(qkv[rb * 1536 + 512 + h * 64 + tid]);
    Vg[tid] = b2f(qkv[rb * 1536 + 1024 + h * 64 + tid]);
  }

  const int q0row = 1 + n * 128 + wid * 32;
  bf16x8 qf[2][2];
  #pragma unroll
  for (int qt = 0; qt < 2; ++qt)
    #pragma unroll
    for (int kk = 0; kk < 2; ++kk)
      qf[qt][kk] = *(const bf16x8*)(qkv + (rb + q0row + qt * 16 + l15) * 1536 + h * 64 + kk * 32 + g * 8);

  __syncthreads();

  float sg[2];
  #pragma unroll
  for (int qt = 0; qt < 2; ++qt) {
    float part = 0.f;
    #pragma unroll
    for (int kk = 0; kk < 2; ++kk)
      #pragma unroll
      for (int i = 0; i < 8; ++i)
        part += b2f((u16)qf[qt][kk][i]) * Kg[kk * 32 + g * 8 + i];
    part += __shfl_xor(part, 16, 64);
    part += __shfl_xor(part, 32, 64);
    sg[qt] = part * 0.125f;
  }

  float m[2] = {-INFINITY, -INFINITY};
  float l[2] = {0.f, 0.f};
  f32x4 of[2][4];
  #pragma unroll
  for (int qt = 0; qt < 2; ++qt)
    #pragma unroll
    for (int dt = 0; dt < 4; ++dt) { f32x4 z = {0.f,0.f,0.f,0.f}; of[qt][dt] = z; }

  for (int dblk = 0; dblk < 3; ++dblk) {
    const int blk = n + dblk - 1;
    if (blk < 0 || blk >= NBLK) continue;
    const size_t krow0 = rb + 1 + (size_t)blk * 128;

    __syncthreads();
    #pragma unroll
    for (int it = 0; it < 4; ++it) {
      int c = it * 256 + tid;
      int key = c >> 3, oct = c & 7;
      *(uint4*)&K_lds[key * 72 + oct * 8] =
          *(const uint4*)(qkv + (krow0 + key) * 1536 + 512 + h * 64 + oct * 8);
    }
    #pragma unroll
    for (int it = 0; it < 2; ++it) {
      int c = it * 256 + tid;
      int kp2 = c & 63, oct = c >> 6;
      const u16* s0 = qkv + (krow0 + 2 * kp2) * 1536 + 1024 + h * 64 + oct * 8;
      uint4 va = *(const uint4*)s0;
      uint4 vb4 = *(const uint4*)(s0 + 1536);
      union { uint4 q; u16 hh[8]; } ua, ub;
      ua.q = va; ub.q = vb4;
      #pragma unroll
      for (int i = 0; i < 8; ++i) {
        u32 w = (u32)ua.hh[i] | ((u32)ub.hh[i] << 16);
        *(u32*)&V_T[(oct * 8 + i) * 136 + 2 * kp2] = w;
      }
    }
    __syncthreads();

    f32x4 st[2][8];
    #pragma unroll
    for (int kt = 0; kt < 8; ++kt) {
      bf16x8 kfr[2];
      #pragma unroll
      for (int kk = 0; kk < 2; ++kk)
        kfr[kk] = *(const bf16x8*)&K_lds[(kt * 16 + l15) * 72 + kk * 32 + g * 8];
      #pragma unroll
      for (int qt = 0; qt < 2; ++qt) {
        f32x4 z = {0.f,0.f,0.f,0.f};
        z = __builtin_amdgcn_mfma_f32_16x16x32_bf16(kfr[0], qf[qt][0], z, 0, 0, 0);
        z = __builtin_amdgcn_mfma_f32_16x16x32_bf16(kfr[1], qf[qt][1], z, 0, 0, 0);
        st[qt][kt] = z;
      }
    }
    #pragma unroll
    for (int qt = 0; qt < 2; ++qt) {
      float bm = -INFINITY;
      #pragma unroll
      for (int kt = 0; kt < 8; ++kt)
        #pragma unroll
        for (int r = 0; r < 4; ++r) bm = fmaxf(bm, st[qt][kt][r]);
      bm = fmaxf(bm, __shfl_xor(bm, 16, 64));
      bm = fmaxf(bm, __shfl_xor(bm, 32, 64));
      bm *= 0.125f;
      float mn = fmaxf(m[qt], bm);
      float corr = __expf(m[qt] - mn);
      float bsum = 0.f;
      #pragma unroll
      for (int kt = 0; kt < 8; ++kt)
        #pragma unroll
        for (int r = 0; r < 4; ++r) {
          float p = __expf(__builtin_fmaf(st[qt][kt][r], 0.125f, -mn));
          st[qt][kt][r] = p;
          bsum += p;
        }
      bsum += __shfl_xor(bsum, 16, 64);
      bsum += __shfl_xor(bsum, 32, 64);
      l[qt] = l[qt] * corr + bsum;
      m[qt] = mn;
      if (lane < 16) bb[wid][0][qt * 16 + lane] = corr;
    }
    float rc[2][4];
    #pragma unroll
    for (int qt = 0; qt < 2; ++qt)
      #pragma unroll
      for (int r = 0; r < 4; ++r) rc[qt][r] = bb[wid][0][qt * 16 + g * 4 + r];
    #pragma unroll
    for (int qt = 0; qt < 2; ++qt)
      #pragma unroll
      for (int dt = 0; dt < 4; ++dt)
        #pragma unroll
        for (int r = 0; r < 4; ++r) of[qt][dt][r] *= rc[qt][r];

    u16* P_w = (u16*)P_lds[wid];
    #pragma unroll
    for (int half = 0; half < 2; ++half) {
      #pragma unroll
      for (int qt = 0; qt < 2; ++qt)
        #pragma unroll
        for (int k4 = 0; k4 < 4; ++k4) {
          int kt = half * 4 + k4;
          u16 h0 = f2b(st[qt][kt][0]), h1 = f2b(st[qt][kt][1]);
          u16 h2 = f2b(st[qt][kt][2]), h3 = f2b(st[qt][kt][3]);
          uint2 pk = { (u32)h0 | ((u32)h1 << 16), (u32)h2 | ((u32)h3 << 16) };
          *(uint2*)&P_w[(qt * 16 + l15) * 72 + k4 * 16 + g * 4] = pk;
        }
      #pragma unroll
      for (int ks = 0; ks < 2; ++ks) {
        bf16x8 pa[2];
        #pragma unroll
        for (int qt = 0; qt < 2; ++qt)
          pa[qt] = *(const bf16x8*)&P_w[(qt * 16 + l15) * 72 + ks * 32 + g * 8];
        #pragma unroll
        for (int dt = 0; dt < 4; ++dt) {
          bf16x8 vb = *(const bf16x8*)&V_T[(dt * 16 + l15) * 136 + half * 64 + ks * 32 + g * 8];
          #pragma unroll
          for (int qt = 0; qt < 2; ++qt)
            of[qt][dt] = __builtin_amdgcn_mfma_f32_16x16x32_bf16(pa[qt], vb, of[qt][dt], 0, 0, 0);
        }
      }
    }
  }

  const int nz = (n == 0) + (n == NBLK - 1);
  #pragma unroll
  for (int qt = 0; qt < 2; ++qt) {
    float mf   = fmaxf(m[qt], sg[qt]);
    float corr = __expf(m[qt] - mf);
    float eg   = __expf(sg[qt] - mf);
    float lf   = l[qt] * corr + eg;
    if (nz) lf += (float)(nz * 128) * __expf(-mf);
    float inv = 1.f / lf;
    if (lane < 16) {
      bb[wid][0][qt * 16 + lane] = corr * inv;
      bb[wid][1][qt * 16 + lane] = eg * inv;
    }
  }
  float vgr[4];
  #pragma unroll
  for (int dt = 0; dt < 4; ++dt) vgr[dt] = Vg[dt * 16 + l15];
  #pragma unroll
  for (int qt = 0; qt < 2; ++qt)
    #pragma unroll
    for (int r = 0; r < 4; ++r) {
      float af = bb[wid][0][qt * 16 + g * 4 + r];
      float bf = bb[wid][1][qt * 16 + g * 4 + r];
      int row = q0row + qt * 16 + g * 4 + r;
      u16* dst = attnb + (rb + row) * 512 + h * 64;
      #pragma unroll
      for (int dt = 0; dt < 4; ++dt)
        dst[dt * 16 + l15] = f2b(of[qt][dt][r] * af + bf * vgr[dt]);
    }
}

extern "C" void kernel_launch(void* const* d_in, const int* in_sizes, int n_in,
                              void* d_out, int out_size, void* d_ws, size_t ws_size,
                              hipStream_t stream) {
  (void)in_sizes; (void)n_in; (void)out_size; (void)ws_size;
  const float* x  = (const float*)d_in[0];
  const float* Wq = (const float*)d_in[1];
  const float* Wk = (const float*)d_in[2];
  const float* Wv = (const float*)d_in[3];
  const float* Wo = (const float*)d_in[4];
  const float* bo = (const float*)d_in[5];
  float* out = (float*)d_out;

  char* ws = (char*)d_ws;
  u16* qkv   = (u16*)ws;
  u16* xb    = (u16*)(ws + 50337792);
  u16* attnb = (u16*)(ws + 50337792);
  u16* WoT   = (u16*)(ws + 67117056);
  u16* WqkvT = (u16*)d_out;                              // scratch; dead before gemm2
  float* gbuf = (float*)((char*)d_out + (4 << 20));      // 33 KB partials

  dim3 blk(256);
  convx<<<dim3(8193), blk, 0, stream>>>(x, xb);
  transposeW<<<dim3(24, 16), blk, 0, stream>>>(Wq, Wk, Wv, 512, WqkvT, 1024);
  gemm8<false><<<dim3(65 * 6), dim3(512), 0, stream>>>(xb, WqkvT, qkv, nullptr, MROWS, 1024, 65, 6, 1536);
  transposeW<<<dim3(16, 8), blk, 0, stream>>>(Wo, Wo, Wo, 1024, WoT, 512);
  gsplit<<<dim3(256), blk, 0, stream>>>(qkv, gbuf);
  gmerge<<<dim3(16), dim3(64), 0, stream>>>(gbuf, attnb);
  local_attn_mfma<<<dim3(1024), blk, 0, stream>>>(qkv, attnb);
  gemm8<true><<<dim3(65 * 4), dim3(512), 0, stream>>>(attnb, WoT, out, bo, MROWS, 512, 65, 4, 1024);
}